// Round 1
// baseline (953.244 us; speedup 1.0000x reference)
//
#include <hip/hip_runtime.h>
#include <math.h>

#define N1 961
#define N2 960
#define KF 240
#define HW2 3844   // 62*62
#define NPIX 15376 // 4*62*62

__device__ __forceinline__ float wave_max(float x) {
  #pragma unroll
  for (int off = 32; off > 0; off >>= 1) x = fmaxf(x, __shfl_xor(x, off, 64));
  return x;
}
__device__ __forceinline__ float wave_sum(float x) {
  #pragma unroll
  for (int off = 32; off > 0; off >>= 1) x += __shfl_xor(x, off, 64);
  return x;
}

__global__ void k_zero(float* p, int n) {
  int i = blockIdx.x * 256 + threadIdx.x;
  if (i < n) p[i] = 0.f;
}

// down conv: x(4,64,64,64) * w_down(128,64,4,4) stride2 -> xd(4,128,31,31)
__global__ __launch_bounds__(256) void k_down(const float* __restrict__ x,
                                              const float* __restrict__ w,
                                              const float* __restrict__ bias,
                                              float* __restrict__ xd) {
  int idx = blockIdx.x * 256 + threadIdx.x;
  if (idx >= 4 * 128 * N1) return;
  int j = idx % 31; int t = idx / 31;
  int i = t % 31; t /= 31;
  int co = t % 128; int b = t / 128;
  float acc = bias[co];
  const float* xb = x + (size_t)b * 64 * 4096 + (2 * i) * 64 + 2 * j;
  const float* wb = w + (size_t)co * 1024;
  for (int ci = 0; ci < 64; ci++) {
    const float* xp = xb + (size_t)ci * 4096;
    const float* wp = wb + ci * 16;
    #pragma unroll
    for (int ky = 0; ky < 4; ky++)
      #pragma unroll
      for (int kx = 0; kx < 4; kx++)
        acc += xp[ky * 64 + kx] * wp[ky * 4 + kx];
  }
  xd[idx] = acc;
}

// attention 1 over N=961 tokens per (b,g), g in 0..31; writes o1 and top-240 idx (g<16)
__global__ __launch_bounds__(256) void k_attn1(const float* __restrict__ xd,
                                               const float* __restrict__ wqkv,
                                               const float* __restrict__ bqkv,
                                               float* __restrict__ o1,
                                               int* __restrict__ topk) {
  __shared__ float qL[4][N1], kL[4][N1], vL[4][N1];
  __shared__ float coarse[1024];
  __shared__ unsigned long long keys[1024];
  __shared__ float Ws[48], Bs[12];
  int tid = threadIdx.x;
  int b = blockIdx.x >> 5, g = blockIdx.x & 31;
  if (tid < 48) Ws[tid] = wqkv[tid];
  if (tid < 12) Bs[tid] = bqkv[tid];
  for (int i = tid; i < 1024; i += 256) coarse[i] = 0.f;
  __syncthreads();
  const float* xp0 = xd + (size_t)(b * 128 + g * 4) * N1;
  for (int n = tid; n < N1; n += 256) {
    float t0 = xp0[n], t1 = xp0[N1 + n], t2 = xp0[2 * N1 + n], t3 = xp0[3 * N1 + n];
    #pragma unroll
    for (int e = 0; e < 4; e++) {
      qL[e][n] = t0 * Ws[e]     + t1 * Ws[12 + e]     + t2 * Ws[24 + e]     + t3 * Ws[36 + e]     + Bs[e];
      kL[e][n] = t0 * Ws[e + 4] + t1 * Ws[12 + e + 4] + t2 * Ws[24 + e + 4] + t3 * Ws[36 + e + 4] + Bs[e + 4];
      vL[e][n] = t0 * Ws[e + 8] + t1 * Ws[12 + e + 8] + t2 * Ws[24 + e + 8] + t3 * Ws[36 + e + 8] + Bs[e + 8];
    }
  }
  __syncthreads();
  int wave = tid >> 6, lane = tid & 63;
  float cacc[16];
  #pragma unroll
  for (int c = 0; c < 16; c++) cacc[c] = 0.f;
  float* o1p = o1 + (size_t)(b * 128 + g * 4) * N1;
  for (int n = wave; n < N1; n += 4) {
    float k0 = kL[0][n], k1 = kL[1][n], k2 = kL[2][n], k3 = kL[3][n];
    float p[16];
    float mx = -INFINITY;
    #pragma unroll
    for (int c = 0; c < 16; c++) {
      int m = c * 64 + lane;
      if (m < N1) {
        float s = k0 * qL[0][m] + k1 * qL[1][m] + k2 * qL[2][m] + k3 * qL[3][m];
        p[c] = s; mx = fmaxf(mx, s);
      } else p[c] = -INFINITY;
    }
    mx = wave_max(mx);
    float sum = 0.f, o0 = 0.f, o1a = 0.f, o2 = 0.f, o3 = 0.f;
    #pragma unroll
    for (int c = 0; c < 16; c++) {
      int m = c * 64 + lane;
      if (m < N1) {
        float e = __expf(p[c] - mx);
        p[c] = e; sum += e;
        o0 += e * vL[0][m]; o1a += e * vL[1][m]; o2 += e * vL[2][m]; o3 += e * vL[3][m];
      }
    }
    sum = wave_sum(sum);
    o0 = wave_sum(o0); o1a = wave_sum(o1a); o2 = wave_sum(o2); o3 = wave_sum(o3);
    float inv = 1.0f / sum;
    if (lane == 0) {
      o1p[n] = o0 * inv; o1p[N1 + n] = o1a * inv;
      o1p[2 * N1 + n] = o2 * inv; o1p[3 * N1 + n] = o3 * inv;
    }
    #pragma unroll
    for (int c = 0; c < 16; c++) {
      int m = c * 64 + lane;
      if (m < N1) cacc[c] += p[c] * inv;
    }
  }
  #pragma unroll
  for (int c = 0; c < 16; c++) {
    int m = c * 64 + lane;
    if (m < N1) atomicAdd(&coarse[m], cacc[c]);
  }
  __syncthreads();
  if (g >= 16) return;
  // top-240 by (value desc, index asc): pack to u64, bitonic ascending sort, take tail
  for (int i = tid; i < 1024; i += 256) {
    unsigned long long key = 0ull;
    if (i < N1) {
      unsigned fb = __float_as_uint(coarse[i]);  // coarse > 0 -> monotone bits
      key = ((unsigned long long)fb << 32) | (unsigned)(N1 - 1 - i);
    }
    keys[i] = key;
  }
  __syncthreads();
  for (int k2 = 2; k2 <= 1024; k2 <<= 1) {
    for (int j = k2 >> 1; j > 0; j >>= 1) {
      for (int i = tid; i < 1024; i += 256) {
        int ixj = i ^ j;
        if (ixj > i) {
          unsigned long long a = keys[i], bb = keys[ixj];
          bool up = ((i & k2) == 0);
          if ((a > bb) == up) { keys[i] = bb; keys[ixj] = a; }
        }
      }
      __syncthreads();
    }
  }
  if (tid < KF) {
    unsigned long long key = keys[1023 - tid];
    topk[(size_t)(b * 16 + g) * KF + tid] = (N1 - 1) - (int)(unsigned)(key & 0xffffffffull);
  }
}

// transposed conv: o1(4,128,31,31) -> yacc = 2*coarse_out (4,64,62,62)
__global__ __launch_bounds__(256) void k_upconv(const float* __restrict__ o1,
                                                const float* __restrict__ w,
                                                const float* __restrict__ bias,
                                                float* __restrict__ yacc) {
  int idx = blockIdx.x * 256 + threadIdx.x;
  if (idx >= 64 * NPIX) return;
  int x = idx % 62; int t = idx / 62;
  int y = t % 62; t /= 62;
  int co = t % 64; int b = t / 64;
  float acc = bias[co];
  for (int u = (y & 1); u < 4; u += 2) {
    int ty = y + u - 2;
    if (ty < 0 || ty > 60) continue;
    int iy = ty >> 1;
    for (int v = (x & 1); v < 4; v += 2) {
      int tx = x + v - 2;
      if (tx < 0 || tx > 60) continue;
      int ix = tx >> 1;
      const float* op = o1 + (size_t)b * 128 * N1 + iy * 31 + ix;
      const float* wp = w + co * 16 + (3 - u) * 4 + (3 - v);
      for (int ci = 0; ci < 128; ci++)
        acc += op[(size_t)ci * N1] * wp[ci * 1024];
    }
  }
  yacc[idx] = 2.0f * acc;
}

// attention 2: gather top-k 2x2 blocks (=0.5*yacc), attend, scatter-add into yacc
__global__ __launch_bounds__(256) void k_attn2(float* __restrict__ yacc,
                                               const float* __restrict__ wqkv,
                                               const float* __restrict__ bqkv,
                                               const int* __restrict__ topk) {
  __shared__ float qL[4][N2], kL[4][N2], vL[4][N2];
  __shared__ int coord[N2];
  __shared__ float Ws[48], Bs[12];
  int tid = threadIdx.x;
  int b = blockIdx.x >> 4, g = blockIdx.x & 15;
  if (tid < 48) Ws[tid] = wqkv[tid];
  if (tid < 12) Bs[tid] = bqkv[tid];
  __syncthreads();
  float* yp0 = yacc + (size_t)(b * 64 + g * 4) * HW2;
  const int* ip = topk + (size_t)(b * 16 + g) * KF;
  for (int n = tid; n < N2; n += 256) {
    int tt = n >> 2, i = (n >> 1) & 1, j = n & 1;
    int p = ip[tt];
    int ph = p / 31, pw = p - ph * 31;
    int cc = (2 * ph + i) * 62 + (2 * pw + j);
    coord[n] = cc;
    float t0 = 0.5f * yp0[cc], t1 = 0.5f * yp0[HW2 + cc];
    float t2 = 0.5f * yp0[2 * HW2 + cc], t3 = 0.5f * yp0[3 * HW2 + cc];
    #pragma unroll
    for (int e = 0; e < 4; e++) {
      qL[e][n] = t0 * Ws[e]     + t1 * Ws[12 + e]     + t2 * Ws[24 + e]     + t3 * Ws[36 + e]     + Bs[e];
      kL[e][n] = t0 * Ws[e + 4] + t1 * Ws[12 + e + 4] + t2 * Ws[24 + e + 4] + t3 * Ws[36 + e + 4] + Bs[e + 4];
      vL[e][n] = t0 * Ws[e + 8] + t1 * Ws[12 + e + 8] + t2 * Ws[24 + e + 8] + t3 * Ws[36 + e + 8] + Bs[e + 8];
    }
  }
  __syncthreads();
  int wave = tid >> 6, lane = tid & 63;
  for (int n = wave; n < N2; n += 4) {
    float k0 = kL[0][n], k1 = kL[1][n], k2 = kL[2][n], k3 = kL[3][n];
    float p[15];
    float mx = -INFINITY;
    #pragma unroll
    for (int c = 0; c < 15; c++) {
      int m = c * 64 + lane;
      float s = k0 * qL[0][m] + k1 * qL[1][m] + k2 * qL[2][m] + k3 * qL[3][m];
      p[c] = s; mx = fmaxf(mx, s);
    }
    mx = wave_max(mx);
    float sum = 0.f, o0 = 0.f, o1a = 0.f, o2 = 0.f, o3 = 0.f;
    #pragma unroll
    for (int c = 0; c < 15; c++) {
      int m = c * 64 + lane;
      float e = __expf(p[c] - mx);
      sum += e;
      o0 += e * vL[0][m]; o1a += e * vL[1][m]; o2 += e * vL[2][m]; o3 += e * vL[3][m];
    }
    sum = wave_sum(sum);
    o0 = wave_sum(o0); o1a = wave_sum(o1a); o2 = wave_sum(o2); o3 = wave_sum(o3);
    float inv = 1.0f / sum;
    if (lane == 0) {
      int cc = coord[n];
      yp0[cc]           += o0 * inv;
      yp0[HW2 + cc]     += o1a * inv;
      yp0[2 * HW2 + cc] += o2 * inv;
      yp0[3 * HW2 + cc] += o3 * inv;
    }
  }
}

// depthwise 3x3, pad 1
__global__ __launch_bounds__(256) void k_dwconv(const float* __restrict__ yin,
                                                const float* __restrict__ w,
                                                float* __restrict__ z1) {
  int idx = blockIdx.x * 256 + threadIdx.x;
  if (idx >= 64 * NPIX) return;
  int x = idx % 62; int t = idx / 62;
  int y = t % 62; t /= 62;
  int c = t % 64;
  int plane = idx / HW2;
  const float* yp = yin + (size_t)plane * HW2;
  const float* wp = w + c * 9;
  float acc = 0.f;
  #pragma unroll
  for (int ky = 0; ky < 3; ky++) {
    int yy = y + ky - 1;
    if (yy < 0 || yy > 61) continue;
    #pragma unroll
    for (int kx = 0; kx < 3; kx++) {
      int xx = x + kx - 1;
      if (xx < 0 || xx > 61) continue;
      acc += yp[yy * 62 + xx] * wp[ky * 3 + kx];
    }
  }
  z1[idx] = acc;
}

// per-channel sum/sumsq over (b,h,w); grid = 64 channels * 4 batches
__global__ __launch_bounds__(256) void k_stats(const float* __restrict__ buf,
                                               float* __restrict__ stats) {
  __shared__ float red[8];
  int c = blockIdx.x >> 2, b = blockIdx.x & 3;
  const float* p = buf + (size_t)(b * 64 + c) * HW2;
  float s = 0.f, s2 = 0.f;
  for (int i = threadIdx.x; i < HW2; i += 256) { float z = p[i]; s += z; s2 += z * z; }
  s = wave_sum(s); s2 = wave_sum(s2);
  int wave = threadIdx.x >> 6, lane = threadIdx.x & 63;
  if (lane == 0) { red[wave] = s; red[4 + wave] = s2; }
  __syncthreads();
  if (threadIdx.x == 0) {
    atomicAdd(&stats[c], red[0] + red[1] + red[2] + red[3]);
    atomicAdd(&stats[64 + c], red[4] + red[5] + red[6] + red[7]);
  }
}

__global__ void k_bnparam(const float* __restrict__ stats, const float* __restrict__ gamma,
                          const float* __restrict__ beta, float* __restrict__ par) {
  int c = threadIdx.x;
  if (c < 64) {
    float m = stats[c] * (1.0f / NPIX);
    float v = stats[64 + c] * (1.0f / NPIX) - m * m;
    float a = gamma[c] * rsqrtf(v + 1e-5f);
    par[c] = a; par[64 + c] = beta[c] - m * a;
  }
}

// pointwise 1x1 on bn_relu6(z1): z2[b,co,p] = sum_ci wpw[co,ci]*clamp(a*z1+c)
__global__ __launch_bounds__(256) void k_pwconv(const float* __restrict__ z1,
                                                const float* __restrict__ wpw,
                                                const float* __restrict__ par,
                                                float* __restrict__ z2) {
  __shared__ float w[4096];
  __shared__ float aa[64], cc[64];
  int tid = threadIdx.x;
  for (int i = tid; i < 4096; i += 256) w[i] = wpw[i];
  if (tid < 64) { aa[tid] = par[tid]; cc[tid] = par[64 + tid]; }
  __syncthreads();
  int pix = blockIdx.x * 256 + tid;
  if (pix >= NPIX) return;
  int b = pix / HW2, p = pix - b * HW2;
  float h[64];
  #pragma unroll
  for (int ci = 0; ci < 64; ci++) {
    float z = z1[(size_t)(b * 64 + ci) * HW2 + p];
    z = aa[ci] * z + cc[ci];
    h[ci] = fminf(fmaxf(z, 0.f), 6.f);
  }
  for (int co = 0; co < 64; co++) {
    float acc = 0.f;
    #pragma unroll
    for (int ci = 0; ci < 64; ci++) acc += h[ci] * w[co * 64 + ci];
    z2[(size_t)(b * 64 + co) * HW2 + p] = acc;
  }
}

__global__ __launch_bounds__(256) void k_final(const float* __restrict__ z2,
                                               const float* __restrict__ par,
                                               float* __restrict__ out) {
  int idx = blockIdx.x * 256 + threadIdx.x;
  if (idx >= 64 * NPIX) return;
  int c = (idx / HW2) & 63;
  float z = par[c] * z2[idx] + par[64 + c];
  out[idx] = fminf(fmaxf(z, 0.f), 6.f);
}

extern "C" void kernel_launch(void* const* d_in, const int* in_sizes, int n_in,
                              void* d_out, int out_size, void* d_ws, size_t ws_size,
                              hipStream_t stream) {
  const float* x       = (const float*)d_in[0];
  const float* w_down  = (const float*)d_in[1];
  const float* b_down  = (const float*)d_in[2];
  const float* w_qkv_c = (const float*)d_in[3];
  const float* b_qkv_c = (const float*)d_in[4];
  const float* w_up    = (const float*)d_in[5];
  const float* b_up    = (const float*)d_in[6];
  const float* w_qkv_t = (const float*)d_in[7];
  const float* b_qkv_t = (const float*)d_in[8];
  const float* w_dw    = (const float*)d_in[9];
  const float* g_dw    = (const float*)d_in[10];
  const float* be_dw   = (const float*)d_in[11];
  const float* w_pw    = (const float*)d_in[12];
  const float* g_pw    = (const float*)d_in[13];
  const float* be_pw   = (const float*)d_in[14];
  float* out = (float*)d_out;

  float* ws    = (float*)d_ws;
  float* xd    = ws;                       // 492032 = 4*128*961
  float* o1    = xd + 492032;              // 492032
  int*   topk  = (int*)(o1 + 492032);      // 15360 = 4*16*240
  float* yacc  = (float*)(topk + 15360);   // 984064 = 4*64*62*62
  float* z1    = yacc + 984064;            // 984064
  float* z2    = z1 + 984064;              // 984064
  float* stats = z2 + 984064;              // 256 (dw sum/sumsq | pw sum/sumsq)
  float* par   = stats + 256;              // 256 (dw a,c | pw a,c)

  k_zero<<<1, 256, 0, stream>>>(stats, 256);
  k_down<<<(4 * 128 * N1 + 255) / 256, 256, 0, stream>>>(x, w_down, b_down, xd);
  k_attn1<<<128, 256, 0, stream>>>(xd, w_qkv_c, b_qkv_c, o1, topk);
  k_upconv<<<(64 * NPIX + 255) / 256, 256, 0, stream>>>(o1, w_up, b_up, yacc);
  k_attn2<<<64, 256, 0, stream>>>(yacc, w_qkv_t, b_qkv_t, topk);
  k_dwconv<<<(64 * NPIX + 255) / 256, 256, 0, stream>>>(yacc, w_dw, z1);
  k_stats<<<256, 256, 0, stream>>>(z1, stats);
  k_bnparam<<<1, 64, 0, stream>>>(stats, g_dw, be_dw, par);
  k_pwconv<<<(NPIX + 255) / 256, 256, 0, stream>>>(z1, w_pw, par, z2);
  k_stats<<<256, 256, 0, stream>>>(z2, stats + 128);
  k_bnparam<<<1, 64, 0, stream>>>(stats + 128, g_pw, be_pw, par + 128);
  k_final<<<(64 * NPIX + 255) / 256, 256, 0, stream>>>(z2, par + 128, out);
}

// Round 2
// 692.168 us; speedup vs baseline: 1.3772x; 1.3772x over previous
//
#include <hip/hip_runtime.h>
#include <math.h>

#define N1 961
#define N2 960
#define KF 240
#define HW2 3844   // 62*62
#define NPIX 15376 // 4*62*62

__global__ void k_zero(float* p, int n) {
  int i = blockIdx.x * 256 + threadIdx.x;
  if (i < n) p[i] = 0.f;
}

// down conv: x(4,64,64,64) * w_down(128,64,4,4) stride2 -> xd(4,128,31,31)
__global__ __launch_bounds__(256) void k_down(const float* __restrict__ x,
                                              const float* __restrict__ w,
                                              const float* __restrict__ bias,
                                              float* __restrict__ xd) {
  int idx = blockIdx.x * 256 + threadIdx.x;
  if (idx >= 4 * 128 * N1) return;
  int j = idx % 31; int t = idx / 31;
  int i = t % 31; t /= 31;
  int co = t % 128; int b = t / 128;
  float acc = bias[co];
  const float* xb = x + (size_t)b * 64 * 4096 + (2 * i) * 64 + 2 * j;
  const float* wb = w + (size_t)co * 1024;
  for (int ci = 0; ci < 64; ci++) {
    const float* xp = xb + (size_t)ci * 4096;
    const float* wp = wb + ci * 16;
    #pragma unroll
    for (int ky = 0; ky < 4; ky++)
      #pragma unroll
      for (int kx = 0; kx < 4; kx++)
        acc += xp[ky * 64 + kx] * wp[ky * 4 + kx];
  }
  xd[idx] = acc;
}

#define QKV_EXPR(off) make_float4( \
    t0 * Ws[(off)] + t1 * Ws[12 + (off)] + t2 * Ws[24 + (off)] + t3 * Ws[36 + (off)] + Bs[(off)], \
    t0 * Ws[(off)+1] + t1 * Ws[12 + (off)+1] + t2 * Ws[24 + (off)+1] + t3 * Ws[36 + (off)+1] + Bs[(off)+1], \
    t0 * Ws[(off)+2] + t1 * Ws[12 + (off)+2] + t2 * Ws[24 + (off)+2] + t3 * Ws[36 + (off)+2] + Bs[(off)+2], \
    t0 * Ws[(off)+3] + t1 * Ws[12 + (off)+3] + t2 * Ws[24 + (off)+3] + t3 * Ws[36 + (off)+3] + Bs[(off)+3])

// attention 1, row-per-thread: block = (b,g,chunk), 512 blocks.
// writes o1 (softmax-normalized outputs) and rowstat (mx, inv) for g<16
__global__ __launch_bounds__(256) void k_attn1(const float* __restrict__ xd,
                                               const float* __restrict__ wqkv,
                                               const float* __restrict__ bqkv,
                                               float* __restrict__ o1,
                                               float2* __restrict__ rowstat) {
  __shared__ float4 qv[N1], kv[N1], vv[N1];
  __shared__ float Ws[48], Bs[12];
  int tid = threadIdx.x;
  int chunk = blockIdx.x & 3;
  int bg = blockIdx.x >> 2;
  int b = bg >> 5, g = bg & 31;
  if (tid < 48) Ws[tid] = wqkv[tid];
  if (tid < 12) Bs[tid] = bqkv[tid];
  __syncthreads();
  const float* xp0 = xd + (size_t)(b * 128 + g * 4) * N1;
  for (int n = tid; n < N1; n += 256) {
    float t0 = xp0[n], t1 = xp0[N1 + n], t2 = xp0[2 * N1 + n], t3 = xp0[3 * N1 + n];
    qv[n] = QKV_EXPR(0);
    kv[n] = QKV_EXPR(4);
    vv[n] = QKV_EXPR(8);
  }
  __syncthreads();
  int n = chunk * 256 + tid;
  if (n >= N1) return;
  float4 kr = kv[n];
  float mx = -INFINITY;
  #pragma unroll 4
  for (int m = 0; m < N1; m++) {
    float4 q = qv[m];
    float s = kr.x * q.x + kr.y * q.y + kr.z * q.z + kr.w * q.w;
    mx = fmaxf(mx, s);
  }
  float sum = 0.f, a0 = 0.f, a1 = 0.f, a2 = 0.f, a3 = 0.f;
  #pragma unroll 4
  for (int m = 0; m < N1; m++) {
    float4 q = qv[m];
    float4 v = vv[m];
    float s = kr.x * q.x + kr.y * q.y + kr.z * q.z + kr.w * q.w;
    float e = __expf(s - mx);
    sum += e;
    a0 += e * v.x; a1 += e * v.y; a2 += e * v.z; a3 += e * v.w;
  }
  float inv = 1.0f / sum;
  float* o1p = o1 + (size_t)(b * 128 + g * 4) * N1;
  o1p[n] = a0 * inv;
  o1p[N1 + n] = a1 * inv;
  o1p[2 * N1 + n] = a2 * inv;
  o1p[3 * N1 + n] = a3 * inv;
  if (g < 16) rowstat[(size_t)(b * 16 + g) * N1 + n] = make_float2(mx, inv);
}

// coarse[m] = sum_n exp(s[n,m]-mx_n)*inv_n, column-per-thread; block=(b,g<16,chunkM), 256 blocks
__global__ __launch_bounds__(256) void k_coarse(const float* __restrict__ xd,
                                                const float* __restrict__ wqkv,
                                                const float* __restrict__ bqkv,
                                                const float2* __restrict__ rowstat,
                                                float* __restrict__ coarse) {
  __shared__ float4 kS[N1];
  __shared__ float2 rs[N1];
  __shared__ float Ws[48], Bs[12];
  int tid = threadIdx.x;
  int chunkM = blockIdx.x & 3;
  int bg = blockIdx.x >> 2;
  int b = bg >> 4, g = bg & 15;
  if (tid < 48) Ws[tid] = wqkv[tid];
  if (tid < 12) Bs[tid] = bqkv[tid];
  __syncthreads();
  const float* xp0 = xd + (size_t)(b * 128 + g * 4) * N1;
  const float2* rp = rowstat + (size_t)(b * 16 + g) * N1;
  for (int n = tid; n < N1; n += 256) {
    float t0 = xp0[n], t1 = xp0[N1 + n], t2 = xp0[2 * N1 + n], t3 = xp0[3 * N1 + n];
    kS[n] = QKV_EXPR(4);
    rs[n] = rp[n];
  }
  __syncthreads();
  int m = chunkM * 256 + tid;
  if (m >= N1) return;
  float t0 = xp0[m], t1 = xp0[N1 + m], t2 = xp0[2 * N1 + m], t3 = xp0[3 * N1 + m];
  float4 q = QKV_EXPR(0);
  float c = 0.f;
  #pragma unroll 4
  for (int n = 0; n < N1; n++) {
    float4 k = kS[n];
    float2 st = rs[n];
    float s = k.x * q.x + k.y * q.y + k.z * q.z + k.w * q.w;
    c += __expf(s - st.x) * st.y;
  }
  coarse[(size_t)(b * 16 + g) * N1 + m] = c;
}

// top-240 per (b,g<16): bitonic over 1024 packed keys
__global__ __launch_bounds__(256) void k_topk(const float* __restrict__ coarse,
                                              int* __restrict__ topk) {
  __shared__ unsigned long long keys[1024];
  int tid = threadIdx.x;
  int bg = blockIdx.x;
  const float* cp = coarse + (size_t)bg * N1;
  for (int i = tid; i < 1024; i += 256) {
    unsigned long long key = 0ull;
    if (i < N1) {
      unsigned fb = __float_as_uint(cp[i]);  // coarse > 0 -> monotone bits
      key = ((unsigned long long)fb << 32) | (unsigned)(N1 - 1 - i);
    }
    keys[i] = key;
  }
  __syncthreads();
  for (int k2 = 2; k2 <= 1024; k2 <<= 1) {
    for (int j = k2 >> 1; j > 0; j >>= 1) {
      for (int i = tid; i < 1024; i += 256) {
        int ixj = i ^ j;
        if (ixj > i) {
          unsigned long long a = keys[i], bb = keys[ixj];
          bool up = ((i & k2) == 0);
          if ((a > bb) == up) { keys[i] = bb; keys[ixj] = a; }
        }
      }
      __syncthreads();
    }
  }
  if (tid < KF) {
    unsigned long long key = keys[1023 - tid];
    topk[(size_t)bg * KF + tid] = (N1 - 1) - (int)(unsigned)(key & 0xffffffffull);
  }
}

// transposed conv: o1(4,128,31,31) -> yacc = 2*coarse_out (4,64,62,62)
__global__ __launch_bounds__(256) void k_upconv(const float* __restrict__ o1,
                                                const float* __restrict__ w,
                                                const float* __restrict__ bias,
                                                float* __restrict__ yacc) {
  int idx = blockIdx.x * 256 + threadIdx.x;
  if (idx >= 64 * NPIX) return;
  int x = idx % 62; int t = idx / 62;
  int y = t % 62; t /= 62;
  int co = t % 64; int b = t / 64;
  float acc = bias[co];
  for (int u = (y & 1); u < 4; u += 2) {
    int ty = y + u - 2;
    if (ty < 0 || ty > 60) continue;
    int iy = ty >> 1;
    for (int v = (x & 1); v < 4; v += 2) {
      int tx = x + v - 2;
      if (tx < 0 || tx > 60) continue;
      int ix = tx >> 1;
      const float* op = o1 + (size_t)b * 128 * N1 + iy * 31 + ix;
      const float* wp = w + co * 16 + (3 - u) * 4 + (3 - v);
      for (int ci = 0; ci < 128; ci++)
        acc += op[(size_t)ci * N1] * wp[ci * 1024];
    }
  }
  yacc[idx] = 2.0f * acc;
}

// attention 2, row-per-thread: block = (b,g,chunk), 256 blocks; output to o2 (+coords)
__global__ __launch_bounds__(256) void k_attn2(const float* __restrict__ yacc,
                                               const float* __restrict__ wqkv,
                                               const float* __restrict__ bqkv,
                                               const int* __restrict__ topk,
                                               float4* __restrict__ o2,
                                               int* __restrict__ coordg) {
  __shared__ float4 qv[N2], kv[N2], vv[N2];
  __shared__ int coordS[N2];
  __shared__ float Ws[48], Bs[12];
  int tid = threadIdx.x;
  int chunk = blockIdx.x & 3;
  int bg = blockIdx.x >> 2;
  int b = bg >> 4, g = bg & 15;
  if (tid < 48) Ws[tid] = wqkv[tid];
  if (tid < 12) Bs[tid] = bqkv[tid];
  __syncthreads();
  const float* yp0 = yacc + (size_t)(b * 64 + g * 4) * HW2;
  const int* ip = topk + (size_t)(b * 16 + g) * KF;
  for (int n = tid; n < N2; n += 256) {
    int tt = n >> 2, i = (n >> 1) & 1, j = n & 1;
    int p = ip[tt];
    int ph = p / 31, pw = p - ph * 31;
    int cc = (2 * ph + i) * 62 + (2 * pw + j);
    coordS[n] = cc;
    float t0 = 0.5f * yp0[cc], t1 = 0.5f * yp0[HW2 + cc];
    float t2 = 0.5f * yp0[2 * HW2 + cc], t3 = 0.5f * yp0[3 * HW2 + cc];
    qv[n] = QKV_EXPR(0);
    kv[n] = QKV_EXPR(4);
    vv[n] = QKV_EXPR(8);
  }
  __syncthreads();
  if (tid >= 240) return;
  int n = chunk * 240 + tid;
  float4 kr = kv[n];
  float mx = -INFINITY;
  #pragma unroll 4
  for (int m = 0; m < N2; m++) {
    float4 q = qv[m];
    float s = kr.x * q.x + kr.y * q.y + kr.z * q.z + kr.w * q.w;
    mx = fmaxf(mx, s);
  }
  float sum = 0.f, a0 = 0.f, a1 = 0.f, a2 = 0.f, a3 = 0.f;
  #pragma unroll 4
  for (int m = 0; m < N2; m++) {
    float4 q = qv[m];
    float4 v = vv[m];
    float s = kr.x * q.x + kr.y * q.y + kr.z * q.z + kr.w * q.w;
    float e = __expf(s - mx);
    sum += e;
    a0 += e * v.x; a1 += e * v.y; a2 += e * v.z; a3 += e * v.w;
  }
  float inv = 1.0f / sum;
  size_t oi = (size_t)(b * 16 + g) * N2 + n;
  o2[oi] = make_float4(a0 * inv, a1 * inv, a2 * inv, a3 * inv);
  coordg[oi] = coordS[n];
}

// scatter-add attn2 output into yacc (disjoint targets, no atomics needed)
__global__ __launch_bounds__(256) void k_scatter(float* __restrict__ yacc,
                                                 const float4* __restrict__ o2,
                                                 const int* __restrict__ coordg) {
  int idx = blockIdx.x * 256 + threadIdx.x;
  if (idx >= 64 * N2) return;
  int bg = idx / N2;
  int b = bg >> 4, g = bg & 15;
  float4 o = o2[idx];
  int cc = coordg[idx];
  float* yp0 = yacc + (size_t)(b * 64 + g * 4) * HW2;
  yp0[cc] += o.x;
  yp0[HW2 + cc] += o.y;
  yp0[2 * HW2 + cc] += o.z;
  yp0[3 * HW2 + cc] += o.w;
}

// depthwise 3x3, pad 1
__global__ __launch_bounds__(256) void k_dwconv(const float* __restrict__ yin,
                                                const float* __restrict__ w,
                                                float* __restrict__ z1) {
  int idx = blockIdx.x * 256 + threadIdx.x;
  if (idx >= 64 * NPIX) return;
  int x = idx % 62; int t = idx / 62;
  int y = t % 62; t /= 62;
  int c = t % 64;
  int plane = idx / HW2;
  const float* yp = yin + (size_t)plane * HW2;
  const float* wp = w + c * 9;
  float acc = 0.f;
  #pragma unroll
  for (int ky = 0; ky < 3; ky++) {
    int yy = y + ky - 1;
    if (yy < 0 || yy > 61) continue;
    #pragma unroll
    for (int kx = 0; kx < 3; kx++) {
      int xx = x + kx - 1;
      if (xx < 0 || xx > 61) continue;
      acc += yp[yy * 62 + xx] * wp[ky * 3 + kx];
    }
  }
  z1[idx] = acc;
}

__device__ __forceinline__ float wave_sum(float x) {
  #pragma unroll
  for (int off = 32; off > 0; off >>= 1) x += __shfl_xor(x, off, 64);
  return x;
}

// per-channel sum/sumsq over (b,h,w); grid = 64 channels * 4 batches
__global__ __launch_bounds__(256) void k_stats(const float* __restrict__ buf,
                                               float* __restrict__ stats) {
  __shared__ float red[8];
  int c = blockIdx.x >> 2, b = blockIdx.x & 3;
  const float* p = buf + (size_t)(b * 64 + c) * HW2;
  float s = 0.f, s2 = 0.f;
  for (int i = threadIdx.x; i < HW2; i += 256) { float z = p[i]; s += z; s2 += z * z; }
  s = wave_sum(s); s2 = wave_sum(s2);
  int wave = threadIdx.x >> 6, lane = threadIdx.x & 63;
  if (lane == 0) { red[wave] = s; red[4 + wave] = s2; }
  __syncthreads();
  if (threadIdx.x == 0) {
    atomicAdd(&stats[c], red[0] + red[1] + red[2] + red[3]);
    atomicAdd(&stats[64 + c], red[4] + red[5] + red[6] + red[7]);
  }
}

__global__ void k_bnparam(const float* __restrict__ stats, const float* __restrict__ gamma,
                          const float* __restrict__ beta, float* __restrict__ par) {
  int c = threadIdx.x;
  if (c < 64) {
    float m = stats[c] * (1.0f / NPIX);
    float v = stats[64 + c] * (1.0f / NPIX) - m * m;
    float a = gamma[c] * rsqrtf(v + 1e-5f);
    par[c] = a; par[64 + c] = beta[c] - m * a;
  }
}

// pointwise 1x1 on bn_relu6(z1)
__global__ __launch_bounds__(256) void k_pwconv(const float* __restrict__ z1,
                                                const float* __restrict__ wpw,
                                                const float* __restrict__ par,
                                                float* __restrict__ z2) {
  __shared__ float w[4096];
  __shared__ float aa[64], cc[64];
  int tid = threadIdx.x;
  for (int i = tid; i < 4096; i += 256) w[i] = wpw[i];
  if (tid < 64) { aa[tid] = par[tid]; cc[tid] = par[64 + tid]; }
  __syncthreads();
  int pix = blockIdx.x * 256 + tid;
  if (pix >= NPIX) return;
  int b = pix / HW2, p = pix - b * HW2;
  float h[64];
  #pragma unroll
  for (int ci = 0; ci < 64; ci++) {
    float z = z1[(size_t)(b * 64 + ci) * HW2 + p];
    z = aa[ci] * z + cc[ci];
    h[ci] = fminf(fmaxf(z, 0.f), 6.f);
  }
  for (int co = 0; co < 64; co++) {
    float acc = 0.f;
    #pragma unroll
    for (int ci = 0; ci < 64; ci++) acc += h[ci] * w[co * 64 + ci];
    z2[(size_t)(b * 64 + co) * HW2 + p] = acc;
  }
}

__global__ __launch_bounds__(256) void k_final(const float* __restrict__ z2,
                                               const float* __restrict__ par,
                                               float* __restrict__ out) {
  int idx = blockIdx.x * 256 + threadIdx.x;
  if (idx >= 64 * NPIX) return;
  int c = (idx / HW2) & 63;
  float z = par[c] * z2[idx] + par[64 + c];
  out[idx] = fminf(fmaxf(z, 0.f), 6.f);
}

extern "C" void kernel_launch(void* const* d_in, const int* in_sizes, int n_in,
                              void* d_out, int out_size, void* d_ws, size_t ws_size,
                              hipStream_t stream) {
  const float* x       = (const float*)d_in[0];
  const float* w_down  = (const float*)d_in[1];
  const float* b_down  = (const float*)d_in[2];
  const float* w_qkv_c = (const float*)d_in[3];
  const float* b_qkv_c = (const float*)d_in[4];
  const float* w_up    = (const float*)d_in[5];
  const float* b_up    = (const float*)d_in[6];
  const float* w_qkv_t = (const float*)d_in[7];
  const float* b_qkv_t = (const float*)d_in[8];
  const float* w_dw    = (const float*)d_in[9];
  const float* g_dw    = (const float*)d_in[10];
  const float* be_dw   = (const float*)d_in[11];
  const float* w_pw    = (const float*)d_in[12];
  const float* g_pw    = (const float*)d_in[13];
  const float* be_pw   = (const float*)d_in[14];
  float* out = (float*)d_out;

  float* ws    = (float*)d_ws;
  float* xd    = ws;                       // 492032 = 4*128*961
  float* o1    = xd + 492032;              // 492032
  int*   topk  = (int*)(o1 + 492032);      // 15360 = 4*16*240
  float* yacc  = (float*)(topk + 15360);   // 984064 = 4*64*62*62
  float* z1    = yacc + 984064;            // 984064 (aliases rowstat+coarse pre-dwconv)
  float* z2    = z1 + 984064;              // 984064 (aliases o2+coordg pre-pwconv)
  float* stats = z2 + 984064;              // 256
  float* par   = stats + 256;              // 256

  // aliases with disjoint lifetimes:
  float2* rowstat = (float2*)z1;                 // 4*16*961 float2 = 123008 floats
  float*  coarse  = z1 + 123008;                 // 4*16*961 = 61504 floats
  float4* o2      = (float4*)z2;                 // 4*16*960 float4 = 245760 floats
  int*    coordg  = (int*)(z2 + 245760);         // 61440 ints

  k_zero<<<1, 256, 0, stream>>>(stats, 256);
  k_down<<<(4 * 128 * N1 + 255) / 256, 256, 0, stream>>>(x, w_down, b_down, xd);
  k_attn1<<<512, 256, 0, stream>>>(xd, w_qkv_c, b_qkv_c, o1, rowstat);
  k_coarse<<<256, 256, 0, stream>>>(xd, w_qkv_c, b_qkv_c, rowstat, coarse);
  k_topk<<<64, 256, 0, stream>>>(coarse, topk);
  k_upconv<<<(64 * NPIX + 255) / 256, 256, 0, stream>>>(o1, w_up, b_up, yacc);
  k_attn2<<<256, 256, 0, stream>>>(yacc, w_qkv_t, b_qkv_t, topk, o2, coordg);
  k_scatter<<<(64 * N2 + 255) / 256, 256, 0, stream>>>(yacc, o2, coordg);
  k_dwconv<<<(64 * NPIX + 255) / 256, 256, 0, stream>>>(yacc, w_dw, z1);
  k_stats<<<256, 256, 0, stream>>>(z1, stats);
  k_bnparam<<<1, 64, 0, stream>>>(stats, g_dw, be_dw, par);
  k_pwconv<<<(NPIX + 255) / 256, 256, 0, stream>>>(z1, w_pw, par, z2);
  k_stats<<<256, 256, 0, stream>>>(z2, stats + 128);
  k_bnparam<<<1, 64, 0, stream>>>(stats + 128, g_pw, be_pw, par + 128);
  k_final<<<(64 * NPIX + 255) / 256, 256, 0, stream>>>(z2, par + 128, out);
}

// Round 3
// 554.271 us; speedup vs baseline: 1.7198x; 1.2488x over previous
//
#include <hip/hip_runtime.h>
#include <math.h>

#define N1 961
#define N2 960
#define KF 240
#define HW2 3844   // 62*62
#define NPIX 15376 // 4*62*62

__global__ void k_zero(float* p, int n) {
  int i = blockIdx.x * 256 + threadIdx.x;
  if (i < n) p[i] = 0.f;
}

// down conv as LDS-tiled implicit GEMM: x(4,64,64,64) * w(128,64,4,4) s2 -> xd(4,128,31,31)
// grid 256 = b(4) x co_half(2) x tile(32: 4 row-tiles of 8 x 8 col-tiles of 4)
// thread: 4 co x 2 px; K staged in 8 ci-chunks of 8
__global__ __launch_bounds__(256) void k_down(const float* __restrict__ x,
                                              const float* __restrict__ w,
                                              const float* __restrict__ bias,
                                              float* __restrict__ xd) {
  __shared__ float iS[8][18][12];
  __shared__ float wS[8 * 16 * 65];
  int tid = threadIdx.x;
  int bid = blockIdx.x;
  int b = bid >> 6;
  int coh = (bid >> 5) & 1;
  int tile = bid & 31;
  int r0 = (tile >> 3) * 8;
  int c0 = (tile & 7) * 4;
  int cg = tid >> 4, p4 = tid & 15;
  int prow = p4 >> 1, pcolb = (p4 & 1) * 2;
  float acc[4][2];
  #pragma unroll
  for (int i = 0; i < 4; i++) { acc[i][0] = 0.f; acc[i][1] = 0.f; }
  const float* xb = x + (size_t)b * 64 * 4096;
  for (int ch = 0; ch < 8; ch++) {
    __syncthreads();
    // input window: rows 2r0..2r0+17, cols 2c0..2c0+9 (zero-fill OOB)
    for (int e = tid; e < 8 * 18 * 10; e += 256) {
      int dx = e % 10; int t = e / 10;
      int dy = t % 18; int ci = t / 18;
      int iy = 2 * r0 + dy, ix = 2 * c0 + dx;
      float v = 0.f;
      if (iy < 64 && ix < 64) v = xb[(size_t)(ch * 8 + ci) * 4096 + iy * 64 + ix];
      iS[ci][dy][dx] = v;
    }
    // weights transposed: wS[(ci*16+tap)*65 + co] = w[(coh*64+co)*1024 + (ch*8+ci)*16 + tap]
    for (int e = tid; e < 8192; e += 256) {
      int tap = e & 15, ci = (e >> 4) & 7, co = e >> 7;
      wS[(ci * 16 + tap) * 65 + co] =
          w[(size_t)(coh * 64 + co) * 1024 + (ch * 8 + ci) * 16 + tap];
    }
    __syncthreads();
    for (int ci = 0; ci < 8; ci++) {
      float xr[4][6];
      #pragma unroll
      for (int ky = 0; ky < 4; ky++)
        #pragma unroll
        for (int xx = 0; xx < 6; xx++)
          xr[ky][xx] = iS[ci][2 * prow + ky][2 * pcolb + xx];
      #pragma unroll
      for (int ky = 0; ky < 4; ky++)
        #pragma unroll
        for (int kx = 0; kx < 4; kx++) {
          const float* wp = &wS[(ci * 16 + ky * 4 + kx) * 65 + cg * 4];
          float w0 = wp[0], w1 = wp[1], w2 = wp[2], w3 = wp[3];
          #pragma unroll
          for (int jj = 0; jj < 2; jj++) {
            float xv = xr[ky][2 * jj + kx];
            acc[0][jj] += w0 * xv; acc[1][jj] += w1 * xv;
            acc[2][jj] += w2 * xv; acc[3][jj] += w3 * xv;
          }
        }
    }
  }
  int i = r0 + prow;
  if (i >= 31) return;
  #pragma unroll
  for (int cc = 0; cc < 4; cc++) {
    int co = coh * 64 + cg * 4 + cc;
    float bv = bias[co];
    #pragma unroll
    for (int jj = 0; jj < 2; jj++) {
      int j = c0 + pcolb + jj;
      if (j < 31) xd[(size_t)(b * 128 + co) * 961 + i * 31 + j] = acc[cc][jj] + bv;
    }
  }
}

#define QKV_EXPR(off) make_float4( \
    t0 * Ws[(off)] + t1 * Ws[12 + (off)] + t2 * Ws[24 + (off)] + t3 * Ws[36 + (off)] + Bs[(off)], \
    t0 * Ws[(off)+1] + t1 * Ws[12 + (off)+1] + t2 * Ws[24 + (off)+1] + t3 * Ws[36 + (off)+1] + Bs[(off)+1], \
    t0 * Ws[(off)+2] + t1 * Ws[12 + (off)+2] + t2 * Ws[24 + (off)+2] + t3 * Ws[36 + (off)+2] + Bs[(off)+2], \
    t0 * Ws[(off)+3] + t1 * Ws[12 + (off)+3] + t2 * Ws[24 + (off)+3] + t3 * Ws[36 + (off)+3] + Bs[(off)+3])

// attention 1, row-per-thread: block = (b,g,chunk), 512 blocks.
__global__ __launch_bounds__(256) void k_attn1(const float* __restrict__ xd,
                                               const float* __restrict__ wqkv,
                                               const float* __restrict__ bqkv,
                                               float* __restrict__ o1,
                                               float2* __restrict__ rowstat) {
  __shared__ float4 qv[N1], kv[N1], vv[N1];
  __shared__ float Ws[48], Bs[12];
  int tid = threadIdx.x;
  int chunk = blockIdx.x & 3;
  int bg = blockIdx.x >> 2;
  int b = bg >> 5, g = bg & 31;
  if (tid < 48) Ws[tid] = wqkv[tid];
  if (tid < 12) Bs[tid] = bqkv[tid];
  __syncthreads();
  const float* xp0 = xd + (size_t)(b * 128 + g * 4) * N1;
  for (int n = tid; n < N1; n += 256) {
    float t0 = xp0[n], t1 = xp0[N1 + n], t2 = xp0[2 * N1 + n], t3 = xp0[3 * N1 + n];
    qv[n] = QKV_EXPR(0);
    kv[n] = QKV_EXPR(4);
    vv[n] = QKV_EXPR(8);
  }
  __syncthreads();
  int n = chunk * 256 + tid;
  if (n >= N1) return;
  float4 kr = kv[n];
  float mx = -INFINITY;
  #pragma unroll 4
  for (int m = 0; m < N1; m++) {
    float4 q = qv[m];
    float s = kr.x * q.x + kr.y * q.y + kr.z * q.z + kr.w * q.w;
    mx = fmaxf(mx, s);
  }
  float sum = 0.f, a0 = 0.f, a1 = 0.f, a2 = 0.f, a3 = 0.f;
  #pragma unroll 4
  for (int m = 0; m < N1; m++) {
    float4 q = qv[m];
    float4 v = vv[m];
    float s = kr.x * q.x + kr.y * q.y + kr.z * q.z + kr.w * q.w;
    float e = __expf(s - mx);
    sum += e;
    a0 += e * v.x; a1 += e * v.y; a2 += e * v.z; a3 += e * v.w;
  }
  float inv = 1.0f / sum;
  float* o1p = o1 + (size_t)(b * 128 + g * 4) * N1;
  o1p[n] = a0 * inv;
  o1p[N1 + n] = a1 * inv;
  o1p[2 * N1 + n] = a2 * inv;
  o1p[3 * N1 + n] = a3 * inv;
  if (g < 16) rowstat[(size_t)(b * 16 + g) * N1 + n] = make_float2(mx, inv);
}

// coarse[m] = sum_n exp(s[n,m]-mx_n)*inv_n
__global__ __launch_bounds__(256) void k_coarse(const float* __restrict__ xd,
                                                const float* __restrict__ wqkv,
                                                const float* __restrict__ bqkv,
                                                const float2* __restrict__ rowstat,
                                                float* __restrict__ coarse) {
  __shared__ float4 kS[N1];
  __shared__ float2 rs[N1];
  __shared__ float Ws[48], Bs[12];
  int tid = threadIdx.x;
  int chunkM = blockIdx.x & 3;
  int bg = blockIdx.x >> 2;
  int b = bg >> 4, g = bg & 15;
  if (tid < 48) Ws[tid] = wqkv[tid];
  if (tid < 12) Bs[tid] = bqkv[tid];
  __syncthreads();
  const float* xp0 = xd + (size_t)(b * 128 + g * 4) * N1;
  const float2* rp = rowstat + (size_t)(b * 16 + g) * N1;
  for (int n = tid; n < N1; n += 256) {
    float t0 = xp0[n], t1 = xp0[N1 + n], t2 = xp0[2 * N1 + n], t3 = xp0[3 * N1 + n];
    kS[n] = QKV_EXPR(4);
    rs[n] = rp[n];
  }
  __syncthreads();
  int m = chunkM * 256 + tid;
  if (m >= N1) return;
  float t0 = xp0[m], t1 = xp0[N1 + m], t2 = xp0[2 * N1 + m], t3 = xp0[3 * N1 + m];
  float4 q = QKV_EXPR(0);
  float c = 0.f;
  #pragma unroll 4
  for (int n = 0; n < N1; n++) {
    float4 k = kS[n];
    float2 st = rs[n];
    float s = k.x * q.x + k.y * q.y + k.z * q.z + k.w * q.w;
    c += __expf(s - st.x) * st.y;
  }
  coarse[(size_t)(b * 16 + g) * N1 + m] = c;
}

// top-240 per (b,g<16): bitonic over 1024 packed keys
__global__ __launch_bounds__(256) void k_topk(const float* __restrict__ coarse,
                                              int* __restrict__ topk) {
  __shared__ unsigned long long keys[1024];
  int tid = threadIdx.x;
  int bg = blockIdx.x;
  const float* cp = coarse + (size_t)bg * N1;
  for (int i = tid; i < 1024; i += 256) {
    unsigned long long key = 0ull;
    if (i < N1) {
      unsigned fb = __float_as_uint(cp[i]);
      key = ((unsigned long long)fb << 32) | (unsigned)(N1 - 1 - i);
    }
    keys[i] = key;
  }
  __syncthreads();
  for (int k2 = 2; k2 <= 1024; k2 <<= 1) {
    for (int j = k2 >> 1; j > 0; j >>= 1) {
      for (int i = tid; i < 1024; i += 256) {
        int ixj = i ^ j;
        if (ixj > i) {
          unsigned long long a = keys[i], bb = keys[ixj];
          bool up = ((i & k2) == 0);
          if ((a > bb) == up) { keys[i] = bb; keys[ixj] = a; }
        }
      }
      __syncthreads();
    }
  }
  if (tid < KF) {
    unsigned long long key = keys[1023 - tid];
    topk[(size_t)bg * KF + tid] = (N1 - 1) - (int)(unsigned)(key & 0xffffffffull);
  }
}

// transposed conv as per-parity 2x2 conv GEMM: o1(4,128,31,31) -> yacc = 2*coarse_out
// grid 256 = b(4) x parity(4) x tile(16: 4x4 of 8x8 px); thread: 4 co x 4 px
__global__ __launch_bounds__(256) void k_upconv(const float* __restrict__ o1,
                                                const float* __restrict__ w,
                                                const float* __restrict__ bias,
                                                float* __restrict__ yacc) {
  __shared__ float iS[16][9][12];
  __shared__ float wS[16 * 4 * 65];
  int tid = threadIdx.x;
  int bid = blockIdx.x;
  int b = bid >> 6;
  int par = (bid >> 4) & 3;
  int py = par >> 1, px = par & 1;
  int tile = bid & 15;
  int r0 = (tile >> 2) * 8;
  int c0 = (tile & 3) * 8;
  int cg = tid >> 4, p4 = tid & 15;
  int prow = p4 >> 1, pcolb = (p4 & 1) * 4;
  int wo[4];
  #pragma unroll
  for (int t = 0; t < 4; t++) {
    int a = t >> 1, d = t & 1;
    wo[t] = (3 - (py + 2 * a)) * 4 + (3 - (px + 2 * d));
  }
  float acc[4][4];
  #pragma unroll
  for (int i = 0; i < 4; i++)
    #pragma unroll
    for (int j = 0; j < 4; j++) acc[i][j] = 0.f;
  const float* ob = o1 + (size_t)b * 128 * N1;
  for (int ch = 0; ch < 8; ch++) {
    __syncthreads();
    // input window: iy = r0+py-1+dy (dy 0..8), ix = c0+px-1+dx (dx 0..8); zero-fill OOB
    for (int e = tid; e < 16 * 81; e += 256) {
      int dx = e % 9; int t = e / 9;
      int dy = t % 9; int ci = t / 9;
      int iy = r0 + py - 1 + dy, ix = c0 + px - 1 + dx;
      float v = 0.f;
      if (iy >= 0 && iy < 31 && ix >= 0 && ix < 31)
        v = ob[(size_t)(ch * 16 + ci) * N1 + iy * 31 + ix];
      iS[ci][dy][dx] = v;
    }
    // weights: wS[(ci*4+tap)*65 + co] = w[(ch*16+ci)*1024 + co*16 + wo[tap]]
    for (int e = tid; e < 16 * 4 * 64; e += 256) {
      int co = e & 63; int t2 = e >> 6;
      int tap = t2 & 3, ci = t2 >> 2;
      wS[(ci * 4 + tap) * 65 + co] = w[(size_t)(ch * 16 + ci) * 1024 + co * 16 + wo[tap]];
    }
    __syncthreads();
    for (int ci = 0; ci < 16; ci++) {
      float xr[2][5];
      #pragma unroll
      for (int a = 0; a < 2; a++)
        #pragma unroll
        for (int xx = 0; xx < 5; xx++)
          xr[a][xx] = iS[ci][prow + a][pcolb + xx];
      #pragma unroll
      for (int t = 0; t < 4; t++) {
        int a = t >> 1, d = t & 1;
        const float* wp = &wS[(ci * 4 + t) * 65 + cg * 4];
        float w0 = wp[0], w1 = wp[1], w2 = wp[2], w3 = wp[3];
        #pragma unroll
        for (int j = 0; j < 4; j++) {
          float xv = xr[a][j + d];
          acc[0][j] += w0 * xv; acc[1][j] += w1 * xv;
          acc[2][j] += w2 * xv; acc[3][j] += w3 * xv;
        }
      }
    }
  }
  int r = r0 + prow;
  if (r >= 31) return;
  int y = 2 * r + py;
  #pragma unroll
  for (int cc = 0; cc < 4; cc++) {
    int co = cg * 4 + cc;
    float bv = bias[co];
    float* yp = yacc + (size_t)(b * 64 + co) * HW2 + y * 62;
    #pragma unroll
    for (int j = 0; j < 4; j++) {
      int c = c0 + pcolb + j;
      if (c < 31) yp[2 * c + px] = 2.0f * (acc[cc][j] + bv);
    }
  }
}

// attention 2, row-per-thread: block = (b,g,chunk), 256 blocks; output to o2 (+coords)
__global__ __launch_bounds__(256) void k_attn2(const float* __restrict__ yacc,
                                               const float* __restrict__ wqkv,
                                               const float* __restrict__ bqkv,
                                               const int* __restrict__ topk,
                                               float4* __restrict__ o2,
                                               int* __restrict__ coordg) {
  __shared__ float4 qv[N2], kv[N2], vv[N2];
  __shared__ int coordS[N2];
  __shared__ float Ws[48], Bs[12];
  int tid = threadIdx.x;
  int chunk = blockIdx.x & 3;
  int bg = blockIdx.x >> 2;
  int b = bg >> 4, g = bg & 15;
  if (tid < 48) Ws[tid] = wqkv[tid];
  if (tid < 12) Bs[tid] = bqkv[tid];
  __syncthreads();
  const float* yp0 = yacc + (size_t)(b * 64 + g * 4) * HW2;
  const int* ip = topk + (size_t)(b * 16 + g) * KF;
  for (int n = tid; n < N2; n += 256) {
    int tt = n >> 2, i = (n >> 1) & 1, j = n & 1;
    int p = ip[tt];
    int ph = p / 31, pw = p - ph * 31;
    int cc = (2 * ph + i) * 62 + (2 * pw + j);
    coordS[n] = cc;
    float t0 = 0.5f * yp0[cc], t1 = 0.5f * yp0[HW2 + cc];
    float t2 = 0.5f * yp0[2 * HW2 + cc], t3 = 0.5f * yp0[3 * HW2 + cc];
    qv[n] = QKV_EXPR(0);
    kv[n] = QKV_EXPR(4);
    vv[n] = QKV_EXPR(8);
  }
  __syncthreads();
  if (tid >= 240) return;
  int n = chunk * 240 + tid;
  float4 kr = kv[n];
  float mx = -INFINITY;
  #pragma unroll 4
  for (int m = 0; m < N2; m++) {
    float4 q = qv[m];
    float s = kr.x * q.x + kr.y * q.y + kr.z * q.z + kr.w * q.w;
    mx = fmaxf(mx, s);
  }
  float sum = 0.f, a0 = 0.f, a1 = 0.f, a2 = 0.f, a3 = 0.f;
  #pragma unroll 4
  for (int m = 0; m < N2; m++) {
    float4 q = qv[m];
    float4 v = vv[m];
    float s = kr.x * q.x + kr.y * q.y + kr.z * q.z + kr.w * q.w;
    float e = __expf(s - mx);
    sum += e;
    a0 += e * v.x; a1 += e * v.y; a2 += e * v.z; a3 += e * v.w;
  }
  float inv = 1.0f / sum;
  size_t oi = (size_t)(b * 16 + g) * N2 + n;
  o2[oi] = make_float4(a0 * inv, a1 * inv, a2 * inv, a3 * inv);
  coordg[oi] = coordS[n];
}

// scatter-add attn2 output into yacc (disjoint targets)
__global__ __launch_bounds__(256) void k_scatter(float* __restrict__ yacc,
                                                 const float4* __restrict__ o2,
                                                 const int* __restrict__ coordg) {
  int idx = blockIdx.x * 256 + threadIdx.x;
  if (idx >= 64 * N2) return;
  int bg = idx / N2;
  int b = bg >> 4, g = bg & 15;
  float4 o = o2[idx];
  int cc = coordg[idx];
  float* yp0 = yacc + (size_t)(b * 64 + g * 4) * HW2;
  yp0[cc] += o.x;
  yp0[HW2 + cc] += o.y;
  yp0[2 * HW2 + cc] += o.z;
  yp0[3 * HW2 + cc] += o.w;
}

// depthwise 3x3, pad 1
__global__ __launch_bounds__(256) void k_dwconv(const float* __restrict__ yin,
                                                const float* __restrict__ w,
                                                float* __restrict__ z1) {
  int idx = blockIdx.x * 256 + threadIdx.x;
  if (idx >= 64 * NPIX) return;
  int x = idx % 62; int t = idx / 62;
  int y = t % 62; t /= 62;
  int c = t % 64;
  int plane = idx / HW2;
  const float* yp = yin + (size_t)plane * HW2;
  const float* wp = w + c * 9;
  float acc = 0.f;
  #pragma unroll
  for (int ky = 0; ky < 3; ky++) {
    int yy = y + ky - 1;
    if (yy < 0 || yy > 61) continue;
    #pragma unroll
    for (int kx = 0; kx < 3; kx++) {
      int xx = x + kx - 1;
      if (xx < 0 || xx > 61) continue;
      acc += yp[yy * 62 + xx] * wp[ky * 3 + kx];
    }
  }
  z1[idx] = acc;
}

__device__ __forceinline__ float wave_sum(float x) {
  #pragma unroll
  for (int off = 32; off > 0; off >>= 1) x += __shfl_xor(x, off, 64);
  return x;
}

__global__ __launch_bounds__(256) void k_stats(const float* __restrict__ buf,
                                               float* __restrict__ stats) {
  __shared__ float red[8];
  int c = blockIdx.x >> 2, b = blockIdx.x & 3;
  const float* p = buf + (size_t)(b * 64 + c) * HW2;
  float s = 0.f, s2 = 0.f;
  for (int i = threadIdx.x; i < HW2; i += 256) { float z = p[i]; s += z; s2 += z * z; }
  s = wave_sum(s); s2 = wave_sum(s2);
  int wave = threadIdx.x >> 6, lane = threadIdx.x & 63;
  if (lane == 0) { red[wave] = s; red[4 + wave] = s2; }
  __syncthreads();
  if (threadIdx.x == 0) {
    atomicAdd(&stats[c], red[0] + red[1] + red[2] + red[3]);
    atomicAdd(&stats[64 + c], red[4] + red[5] + red[6] + red[7]);
  }
}

__global__ void k_bnparam(const float* __restrict__ stats, const float* __restrict__ gamma,
                          const float* __restrict__ beta, float* __restrict__ par) {
  int c = threadIdx.x;
  if (c < 64) {
    float m = stats[c] * (1.0f / NPIX);
    float v = stats[64 + c] * (1.0f / NPIX) - m * m;
    float a = gamma[c] * rsqrtf(v + 1e-5f);
    par[c] = a; par[64 + c] = beta[c] - m * a;
  }
}

__global__ __launch_bounds__(256) void k_pwconv(const float* __restrict__ z1,
                                                const float* __restrict__ wpw,
                                                const float* __restrict__ par,
                                                float* __restrict__ z2) {
  __shared__ float w[4096];
  __shared__ float aa[64], cc[64];
  int tid = threadIdx.x;
  for (int i = tid; i < 4096; i += 256) w[i] = wpw[i];
  if (tid < 64) { aa[tid] = par[tid]; cc[tid] = par[64 + tid]; }
  __syncthreads();
  int pix = blockIdx.x * 256 + tid;
  if (pix >= NPIX) return;
  int b = pix / HW2, p = pix - b * HW2;
  float h[64];
  #pragma unroll
  for (int ci = 0; ci < 64; ci++) {
    float z = z1[(size_t)(b * 64 + ci) * HW2 + p];
    z = aa[ci] * z + cc[ci];
    h[ci] = fminf(fmaxf(z, 0.f), 6.f);
  }
  for (int co = 0; co < 64; co++) {
    float acc = 0.f;
    #pragma unroll
    for (int ci = 0; ci < 64; ci++) acc += h[ci] * w[co * 64 + ci];
    z2[(size_t)(b * 64 + co) * HW2 + p] = acc;
  }
}

__global__ __launch_bounds__(256) void k_final(const float* __restrict__ z2,
                                               const float* __restrict__ par,
                                               float* __restrict__ out) {
  int idx = blockIdx.x * 256 + threadIdx.x;
  if (idx >= 64 * NPIX) return;
  int c = (idx / HW2) & 63;
  float z = par[c] * z2[idx] + par[64 + c];
  out[idx] = fminf(fmaxf(z, 0.f), 6.f);
}

extern "C" void kernel_launch(void* const* d_in, const int* in_sizes, int n_in,
                              void* d_out, int out_size, void* d_ws, size_t ws_size,
                              hipStream_t stream) {
  const float* x       = (const float*)d_in[0];
  const float* w_down  = (const float*)d_in[1];
  const float* b_down  = (const float*)d_in[2];
  const float* w_qkv_c = (const float*)d_in[3];
  const float* b_qkv_c = (const float*)d_in[4];
  const float* w_up    = (const float*)d_in[5];
  const float* b_up    = (const float*)d_in[6];
  const float* w_qkv_t = (const float*)d_in[7];
  const float* b_qkv_t = (const float*)d_in[8];
  const float* w_dw    = (const float*)d_in[9];
  const float* g_dw    = (const float*)d_in[10];
  const float* be_dw   = (const float*)d_in[11];
  const float* w_pw    = (const float*)d_in[12];
  const float* g_pw    = (const float*)d_in[13];
  const float* be_pw   = (const float*)d_in[14];
  float* out = (float*)d_out;

  float* ws    = (float*)d_ws;
  float* xd    = ws;                       // 492032 = 4*128*961
  float* o1    = xd + 492032;              // 492032
  int*   topk  = (int*)(o1 + 492032);      // 15360 = 4*16*240
  float* yacc  = (float*)(topk + 15360);   // 984064 = 4*64*62*62
  float* z1    = yacc + 984064;            // 984064 (aliases rowstat+coarse pre-dwconv)
  float* z2    = z1 + 984064;              // 984064 (aliases o2+coordg pre-pwconv)
  float* stats = z2 + 984064;              // 256
  float* par   = stats + 256;              // 256

  float2* rowstat = (float2*)z1;
  float*  coarse  = z1 + 123008;
  float4* o2      = (float4*)z2;
  int*    coordg  = (int*)(z2 + 245760);

  k_zero<<<1, 256, 0, stream>>>(stats, 256);
  k_down<<<256, 256, 0, stream>>>(x, w_down, b_down, xd);
  k_attn1<<<512, 256, 0, stream>>>(xd, w_qkv_c, b_qkv_c, o1, rowstat);
  k_coarse<<<256, 256, 0, stream>>>(xd, w_qkv_c, b_qkv_c, rowstat, coarse);
  k_topk<<<64, 256, 0, stream>>>(coarse, topk);
  k_upconv<<<256, 256, 0, stream>>>(o1, w_up, b_up, yacc);
  k_attn2<<<256, 256, 0, stream>>>(yacc, w_qkv_t, b_qkv_t, topk, o2, coordg);
  k_scatter<<<(64 * N2 + 255) / 256, 256, 0, stream>>>(yacc, o2, coordg);
  k_dwconv<<<(64 * NPIX + 255) / 256, 256, 0, stream>>>(yacc, w_dw, z1);
  k_stats<<<256, 256, 0, stream>>>(z1, stats);
  k_bnparam<<<1, 64, 0, stream>>>(stats, g_dw, be_dw, par);
  k_pwconv<<<(NPIX + 255) / 256, 256, 0, stream>>>(z1, w_pw, par, z2);
  k_stats<<<256, 256, 0, stream>>>(z2, stats + 128);
  k_bnparam<<<1, 64, 0, stream>>>(stats + 128, g_pw, be_pw, par + 128);
  k_final<<<(64 * NPIX + 255) / 256, 256, 0, stream>>>(z2, par + 128, out);
}

// Round 4
// 426.968 us; speedup vs baseline: 2.2326x; 1.2982x over previous
//
#include <hip/hip_runtime.h>
#include <math.h>

#define N1 961
#define N2 960
#define KF 240
#define HW2 3844   // 62*62
#define NPIX 15376 // 4*62*62

__global__ void k_zero(float* p, int n) {
  int i = blockIdx.x * 256 + threadIdx.x;
  if (i < n) p[i] = 0.f;
}

// down conv as LDS-tiled implicit GEMM: x(4,64,64,64) * w(128,64,4,4) s2 -> xd(4,128,31,31)
__global__ __launch_bounds__(256) void k_down(const float* __restrict__ x,
                                              const float* __restrict__ w,
                                              const float* __restrict__ bias,
                                              float* __restrict__ xd) {
  __shared__ float iS[8][18][12];
  __shared__ float wS[8 * 16 * 65];
  int tid = threadIdx.x;
  int bid = blockIdx.x;
  int b = bid >> 6;
  int coh = (bid >> 5) & 1;
  int tile = bid & 31;
  int r0 = (tile >> 3) * 8;
  int c0 = (tile & 7) * 4;
  int cg = tid >> 4, p4 = tid & 15;
  int prow = p4 >> 1, pcolb = (p4 & 1) * 2;
  float acc[4][2];
  #pragma unroll
  for (int i = 0; i < 4; i++) { acc[i][0] = 0.f; acc[i][1] = 0.f; }
  const float* xb = x + (size_t)b * 64 * 4096;
  for (int ch = 0; ch < 8; ch++) {
    __syncthreads();
    for (int e = tid; e < 8 * 18 * 10; e += 256) {
      int dx = e % 10; int t = e / 10;
      int dy = t % 18; int ci = t / 18;
      int iy = 2 * r0 + dy, ix = 2 * c0 + dx;
      float v = 0.f;
      if (iy < 64 && ix < 64) v = xb[(size_t)(ch * 8 + ci) * 4096 + iy * 64 + ix];
      iS[ci][dy][dx] = v;
    }
    for (int e = tid; e < 8192; e += 256) {
      int tap = e & 15, ci = (e >> 4) & 7, co = e >> 7;
      wS[(ci * 16 + tap) * 65 + co] =
          w[(size_t)(coh * 64 + co) * 1024 + (ch * 8 + ci) * 16 + tap];
    }
    __syncthreads();
    for (int ci = 0; ci < 8; ci++) {
      float xr[4][6];
      #pragma unroll
      for (int ky = 0; ky < 4; ky++)
        #pragma unroll
        for (int xx = 0; xx < 6; xx++)
          xr[ky][xx] = iS[ci][2 * prow + ky][2 * pcolb + xx];
      #pragma unroll
      for (int ky = 0; ky < 4; ky++)
        #pragma unroll
        for (int kx = 0; kx < 4; kx++) {
          const float* wp = &wS[(ci * 16 + ky * 4 + kx) * 65 + cg * 4];
          float w0 = wp[0], w1 = wp[1], w2 = wp[2], w3 = wp[3];
          #pragma unroll
          for (int jj = 0; jj < 2; jj++) {
            float xv = xr[ky][2 * jj + kx];
            acc[0][jj] += w0 * xv; acc[1][jj] += w1 * xv;
            acc[2][jj] += w2 * xv; acc[3][jj] += w3 * xv;
          }
        }
    }
  }
  int i = r0 + prow;
  if (i >= 31) return;
  #pragma unroll
  for (int cc = 0; cc < 4; cc++) {
    int co = coh * 64 + cg * 4 + cc;
    float bv = bias[co];
    #pragma unroll
    for (int jj = 0; jj < 2; jj++) {
      int j = c0 + pcolb + jj;
      if (j < 31) xd[(size_t)(b * 128 + co) * 961 + i * 31 + j] = acc[cc][jj] + bv;
    }
  }
}

#define QKV_EXPR(off) make_float4( \
    t0 * Ws[(off)] + t1 * Ws[12 + (off)] + t2 * Ws[24 + (off)] + t3 * Ws[36 + (off)] + Bs[(off)], \
    t0 * Ws[(off)+1] + t1 * Ws[12 + (off)+1] + t2 * Ws[24 + (off)+1] + t3 * Ws[36 + (off)+1] + Bs[(off)+1], \
    t0 * Ws[(off)+2] + t1 * Ws[12 + (off)+2] + t2 * Ws[24 + (off)+2] + t3 * Ws[36 + (off)+2] + Bs[(off)+2], \
    t0 * Ws[(off)+3] + t1 * Ws[12 + (off)+3] + t2 * Ws[24 + (off)+3] + t3 * Ws[36 + (off)+3] + Bs[(off)+3])

// attention 1, single-pass (no max subtraction — scores bounded, fp32 exp safe).
// row-per-thread; block = (b,g,chunk), 512 blocks. rowstat = 1/sum (g<16).
__global__ __launch_bounds__(256) void k_attn1(const float* __restrict__ xd,
                                               const float* __restrict__ wqkv,
                                               const float* __restrict__ bqkv,
                                               float* __restrict__ o1,
                                               float* __restrict__ rowstat) {
  __shared__ float4 qvv[2 * N1];  // interleaved q,v: one address register, two imm offsets
  __shared__ float4 kv[N1];
  __shared__ float Ws[48], Bs[12];
  int tid = threadIdx.x;
  int chunk = blockIdx.x & 3;
  int bg = blockIdx.x >> 2;
  int b = bg >> 5, g = bg & 31;
  if (tid < 48) Ws[tid] = wqkv[tid];
  if (tid < 12) Bs[tid] = bqkv[tid];
  __syncthreads();
  const float* xp0 = xd + (size_t)(b * 128 + g * 4) * N1;
  for (int n = tid; n < N1; n += 256) {
    float t0 = xp0[n], t1 = xp0[N1 + n], t2 = xp0[2 * N1 + n], t3 = xp0[3 * N1 + n];
    qvv[2 * n]     = QKV_EXPR(0);
    qvv[2 * n + 1] = QKV_EXPR(8);
    kv[n] = QKV_EXPR(4);
  }
  __syncthreads();
  int n = chunk * 256 + tid;
  if (n >= N1) return;
  float4 kr = kv[n];
  float sum = 0.f, a0 = 0.f, a1 = 0.f, a2 = 0.f, a3 = 0.f;
  #pragma unroll 8
  for (int m = 0; m < N1; m++) {
    float4 q = qvv[2 * m];
    float4 v = qvv[2 * m + 1];
    float s = kr.x * q.x + kr.y * q.y + kr.z * q.z + kr.w * q.w;
    float e = __expf(s);
    sum += e;
    a0 += e * v.x; a1 += e * v.y; a2 += e * v.z; a3 += e * v.w;
  }
  float inv = 1.0f / sum;
  float* o1p = o1 + (size_t)(b * 128 + g * 4) * N1;
  o1p[n] = a0 * inv;
  o1p[N1 + n] = a1 * inv;
  o1p[2 * N1 + n] = a2 * inv;
  o1p[3 * N1 + n] = a3 * inv;
  if (g < 16) rowstat[(size_t)(b * 16 + g) * N1 + n] = inv;
}

// coarse[m] = sum_n exp(s[n,m])*inv_n (single-pass convention)
__global__ __launch_bounds__(256) void k_coarse(const float* __restrict__ xd,
                                                const float* __restrict__ wqkv,
                                                const float* __restrict__ bqkv,
                                                const float* __restrict__ rowstat,
                                                float* __restrict__ coarse) {
  __shared__ float4 kS[N1];
  __shared__ float rs[N1];
  __shared__ float Ws[48], Bs[12];
  int tid = threadIdx.x;
  int chunkM = blockIdx.x & 3;
  int bg = blockIdx.x >> 2;
  int b = bg >> 4, g = bg & 15;
  if (tid < 48) Ws[tid] = wqkv[tid];
  if (tid < 12) Bs[tid] = bqkv[tid];
  __syncthreads();
  const float* xp0 = xd + (size_t)(b * 128 + g * 4) * N1;
  const float* rp = rowstat + (size_t)(b * 16 + g) * N1;
  for (int n = tid; n < N1; n += 256) {
    float t0 = xp0[n], t1 = xp0[N1 + n], t2 = xp0[2 * N1 + n], t3 = xp0[3 * N1 + n];
    kS[n] = QKV_EXPR(4);
    rs[n] = rp[n];
  }
  __syncthreads();
  int m = chunkM * 256 + tid;
  if (m >= N1) return;
  float t0 = xp0[m], t1 = xp0[N1 + m], t2 = xp0[2 * N1 + m], t3 = xp0[3 * N1 + m];
  float4 q = QKV_EXPR(0);
  float c = 0.f;
  #pragma unroll 8
  for (int n = 0; n < N1; n++) {
    float4 k = kS[n];
    float s = k.x * q.x + k.y * q.y + k.z * q.z + k.w * q.w;
    c += __expf(s) * rs[n];
  }
  coarse[(size_t)(b * 16 + g) * N1 + m] = c;
}

// top-240 per (b,g<16): bitonic over 1024 packed keys
__global__ __launch_bounds__(256) void k_topk(const float* __restrict__ coarse,
                                              int* __restrict__ topk) {
  __shared__ unsigned long long keys[1024];
  int tid = threadIdx.x;
  int bg = blockIdx.x;
  const float* cp = coarse + (size_t)bg * N1;
  for (int i = tid; i < 1024; i += 256) {
    unsigned long long key = 0ull;
    if (i < N1) {
      unsigned fb = __float_as_uint(cp[i]);
      key = ((unsigned long long)fb << 32) | (unsigned)(N1 - 1 - i);
    }
    keys[i] = key;
  }
  __syncthreads();
  for (int k2 = 2; k2 <= 1024; k2 <<= 1) {
    for (int j = k2 >> 1; j > 0; j >>= 1) {
      for (int i = tid; i < 1024; i += 256) {
        int ixj = i ^ j;
        if (ixj > i) {
          unsigned long long a = keys[i], bb = keys[ixj];
          bool up = ((i & k2) == 0);
          if ((a > bb) == up) { keys[i] = bb; keys[ixj] = a; }
        }
      }
      __syncthreads();
    }
  }
  if (tid < KF) {
    unsigned long long key = keys[1023 - tid];
    topk[(size_t)bg * KF + tid] = (N1 - 1) - (int)(unsigned)(key & 0xffffffffull);
  }
}

// transposed conv as per-parity 2x2 conv GEMM: o1(4,128,31,31) -> yacc = 2*coarse_out
__global__ __launch_bounds__(256) void k_upconv(const float* __restrict__ o1,
                                                const float* __restrict__ w,
                                                const float* __restrict__ bias,
                                                float* __restrict__ yacc) {
  __shared__ float iS[16][9][12];
  __shared__ float wS[16 * 4 * 65];
  int tid = threadIdx.x;
  int bid = blockIdx.x;
  int b = bid >> 6;
  int par = (bid >> 4) & 3;
  int py = par >> 1, px = par & 1;
  int tile = bid & 15;
  int r0 = (tile >> 2) * 8;
  int c0 = (tile & 3) * 8;
  int cg = tid >> 4, p4 = tid & 15;
  int prow = p4 >> 1, pcolb = (p4 & 1) * 4;
  int wo[4];
  #pragma unroll
  for (int t = 0; t < 4; t++) {
    int a = t >> 1, d = t & 1;
    wo[t] = (3 - (py + 2 * a)) * 4 + (3 - (px + 2 * d));
  }
  float acc[4][4];
  #pragma unroll
  for (int i = 0; i < 4; i++)
    #pragma unroll
    for (int j = 0; j < 4; j++) acc[i][j] = 0.f;
  const float* ob = o1 + (size_t)b * 128 * N1;
  for (int ch = 0; ch < 8; ch++) {
    __syncthreads();
    for (int e = tid; e < 16 * 81; e += 256) {
      int dx = e % 9; int t = e / 9;
      int dy = t % 9; int ci = t / 9;
      int iy = r0 + py - 1 + dy, ix = c0 + px - 1 + dx;
      float v = 0.f;
      if (iy >= 0 && iy < 31 && ix >= 0 && ix < 31)
        v = ob[(size_t)(ch * 16 + ci) * N1 + iy * 31 + ix];
      iS[ci][dy][dx] = v;
    }
    for (int e = tid; e < 16 * 4 * 64; e += 256) {
      int co = e & 63; int t2 = e >> 6;
      int tap = t2 & 3, ci = t2 >> 2;
      wS[(ci * 4 + tap) * 65 + co] = w[(size_t)(ch * 16 + ci) * 1024 + co * 16 + wo[tap]];
    }
    __syncthreads();
    for (int ci = 0; ci < 16; ci++) {
      float xr[2][5];
      #pragma unroll
      for (int a = 0; a < 2; a++)
        #pragma unroll
        for (int xx = 0; xx < 5; xx++)
          xr[a][xx] = iS[ci][prow + a][pcolb + xx];
      #pragma unroll
      for (int t = 0; t < 4; t++) {
        int a = t >> 1, d = t & 1;
        const float* wp = &wS[(ci * 4 + t) * 65 + cg * 4];
        float w0 = wp[0], w1 = wp[1], w2 = wp[2], w3 = wp[3];
        #pragma unroll
        for (int j = 0; j < 4; j++) {
          float xv = xr[a][j + d];
          acc[0][j] += w0 * xv; acc[1][j] += w1 * xv;
          acc[2][j] += w2 * xv; acc[3][j] += w3 * xv;
        }
      }
    }
  }
  int r = r0 + prow;
  if (r >= 31) return;
  int y = 2 * r + py;
  #pragma unroll
  for (int cc = 0; cc < 4; cc++) {
    int co = cg * 4 + cc;
    float bv = bias[co];
    float* yp = yacc + (size_t)(b * 64 + co) * HW2 + y * 62;
    #pragma unroll
    for (int j = 0; j < 4; j++) {
      int c = c0 + pcolb + j;
      if (c < 31) yp[2 * c + px] = 2.0f * (acc[cc][j] + bv);
    }
  }
}

// attention 2, single-pass, row-per-thread; 256 blocks; output to o2 (+coords)
__global__ __launch_bounds__(256) void k_attn2(const float* __restrict__ yacc,
                                               const float* __restrict__ wqkv,
                                               const float* __restrict__ bqkv,
                                               const int* __restrict__ topk,
                                               float4* __restrict__ o2,
                                               int* __restrict__ coordg) {
  __shared__ float4 qvv[2 * N2];
  __shared__ float4 kv[N2];
  __shared__ int coordS[N2];
  __shared__ float Ws[48], Bs[12];
  int tid = threadIdx.x;
  int chunk = blockIdx.x & 3;
  int bg = blockIdx.x >> 2;
  int b = bg >> 4, g = bg & 15;
  if (tid < 48) Ws[tid] = wqkv[tid];
  if (tid < 12) Bs[tid] = bqkv[tid];
  __syncthreads();
  const float* yp0 = yacc + (size_t)(b * 64 + g * 4) * HW2;
  const int* ip = topk + (size_t)(b * 16 + g) * KF;
  for (int n = tid; n < N2; n += 256) {
    int tt = n >> 2, i = (n >> 1) & 1, j = n & 1;
    int p = ip[tt];
    int ph = p / 31, pw = p - ph * 31;
    int cc = (2 * ph + i) * 62 + (2 * pw + j);
    coordS[n] = cc;
    float t0 = 0.5f * yp0[cc], t1 = 0.5f * yp0[HW2 + cc];
    float t2 = 0.5f * yp0[2 * HW2 + cc], t3 = 0.5f * yp0[3 * HW2 + cc];
    qvv[2 * n]     = QKV_EXPR(0);
    qvv[2 * n + 1] = QKV_EXPR(8);
    kv[n] = QKV_EXPR(4);
  }
  __syncthreads();
  if (tid >= 240) return;
  int n = chunk * 240 + tid;
  float4 kr = kv[n];
  float sum = 0.f, a0 = 0.f, a1 = 0.f, a2 = 0.f, a3 = 0.f;
  #pragma unroll 8
  for (int m = 0; m < N2; m++) {
    float4 q = qvv[2 * m];
    float4 v = qvv[2 * m + 1];
    float s = kr.x * q.x + kr.y * q.y + kr.z * q.z + kr.w * q.w;
    float e = __expf(s);
    sum += e;
    a0 += e * v.x; a1 += e * v.y; a2 += e * v.z; a3 += e * v.w;
  }
  float inv = 1.0f / sum;
  size_t oi = (size_t)(b * 16 + g) * N2 + n;
  o2[oi] = make_float4(a0 * inv, a1 * inv, a2 * inv, a3 * inv);
  coordg[oi] = coordS[n];
}

// scatter-add attn2 output into yacc (disjoint targets)
__global__ __launch_bounds__(256) void k_scatter(float* __restrict__ yacc,
                                                 const float4* __restrict__ o2,
                                                 const int* __restrict__ coordg) {
  int idx = blockIdx.x * 256 + threadIdx.x;
  if (idx >= 64 * N2) return;
  int bg = idx / N2;
  int b = bg >> 4, g = bg & 15;
  float4 o = o2[idx];
  int cc = coordg[idx];
  float* yp0 = yacc + (size_t)(b * 64 + g * 4) * HW2;
  yp0[cc] += o.x;
  yp0[HW2 + cc] += o.y;
  yp0[2 * HW2 + cc] += o.z;
  yp0[3 * HW2 + cc] += o.w;
}

// depthwise 3x3, pad 1
__global__ __launch_bounds__(256) void k_dwconv(const float* __restrict__ yin,
                                                const float* __restrict__ w,
                                                float* __restrict__ z1) {
  int idx = blockIdx.x * 256 + threadIdx.x;
  if (idx >= 64 * NPIX) return;
  int x = idx % 62; int t = idx / 62;
  int y = t % 62; t /= 62;
  int c = t % 64;
  int plane = idx / HW2;
  const float* yp = yin + (size_t)plane * HW2;
  const float* wp = w + c * 9;
  float acc = 0.f;
  #pragma unroll
  for (int ky = 0; ky < 3; ky++) {
    int yy = y + ky - 1;
    if (yy < 0 || yy > 61) continue;
    #pragma unroll
    for (int kx = 0; kx < 3; kx++) {
      int xx = x + kx - 1;
      if (xx < 0 || xx > 61) continue;
      acc += yp[yy * 62 + xx] * wp[ky * 3 + kx];
    }
  }
  z1[idx] = acc;
}

__device__ __forceinline__ float wave_sum(float x) {
  #pragma unroll
  for (int off = 32; off > 0; off >>= 1) x += __shfl_xor(x, off, 64);
  return x;
}

__global__ __launch_bounds__(256) void k_stats(const float* __restrict__ buf,
                                               float* __restrict__ stats) {
  __shared__ float red[8];
  int c = blockIdx.x >> 2, b = blockIdx.x & 3;
  const float* p = buf + (size_t)(b * 64 + c) * HW2;
  float s = 0.f, s2 = 0.f;
  for (int i = threadIdx.x; i < HW2; i += 256) { float z = p[i]; s += z; s2 += z * z; }
  s = wave_sum(s); s2 = wave_sum(s2);
  int wave = threadIdx.x >> 6, lane = threadIdx.x & 63;
  if (lane == 0) { red[wave] = s; red[4 + wave] = s2; }
  __syncthreads();
  if (threadIdx.x == 0) {
    atomicAdd(&stats[c], red[0] + red[1] + red[2] + red[3]);
    atomicAdd(&stats[64 + c], red[4] + red[5] + red[6] + red[7]);
  }
}

__global__ void k_bnparam(const float* __restrict__ stats, const float* __restrict__ gamma,
                          const float* __restrict__ beta, float* __restrict__ par) {
  int c = threadIdx.x;
  if (c < 64) {
    float m = stats[c] * (1.0f / NPIX);
    float v = stats[64 + c] * (1.0f / NPIX) - m * m;
    float a = gamma[c] * rsqrtf(v + 1e-5f);
    par[c] = a; par[64 + c] = beta[c] - m * a;
  }
}

__global__ __launch_bounds__(256) void k_pwconv(const float* __restrict__ z1,
                                                const float* __restrict__ wpw,
                                                const float* __restrict__ par,
                                                float* __restrict__ z2) {
  __shared__ float w[4096];
  __shared__ float aa[64], cc[64];
  int tid = threadIdx.x;
  for (int i = tid; i < 4096; i += 256) w[i] = wpw[i];
  if (tid < 64) { aa[tid] = par[tid]; cc[tid] = par[64 + tid]; }
  __syncthreads();
  int pix = blockIdx.x * 256 + tid;
  if (pix >= NPIX) return;
  int b = pix / HW2, p = pix - b * HW2;
  float h[64];
  #pragma unroll
  for (int ci = 0; ci < 64; ci++) {
    float z = z1[(size_t)(b * 64 + ci) * HW2 + p];
    z = aa[ci] * z + cc[ci];
    h[ci] = fminf(fmaxf(z, 0.f), 6.f);
  }
  for (int co = 0; co < 64; co++) {
    float acc = 0.f;
    #pragma unroll
    for (int ci = 0; ci < 64; ci++) acc += h[ci] * w[co * 64 + ci];
    z2[(size_t)(b * 64 + co) * HW2 + p] = acc;
  }
}

__global__ __launch_bounds__(256) void k_final(const float* __restrict__ z2,
                                               const float* __restrict__ par,
                                               float* __restrict__ out) {
  int idx = blockIdx.x * 256 + threadIdx.x;
  if (idx >= 64 * NPIX) return;
  int c = (idx / HW2) & 63;
  float z = par[c] * z2[idx] + par[64 + c];
  out[idx] = fminf(fmaxf(z, 0.f), 6.f);
}

extern "C" void kernel_launch(void* const* d_in, const int* in_sizes, int n_in,
                              void* d_out, int out_size, void* d_ws, size_t ws_size,
                              hipStream_t stream) {
  const float* x       = (const float*)d_in[0];
  const float* w_down  = (const float*)d_in[1];
  const float* b_down  = (const float*)d_in[2];
  const float* w_qkv_c = (const float*)d_in[3];
  const float* b_qkv_c = (const float*)d_in[4];
  const float* w_up    = (const float*)d_in[5];
  const float* b_up    = (const float*)d_in[6];
  const float* w_qkv_t = (const float*)d_in[7];
  const float* b_qkv_t = (const float*)d_in[8];
  const float* w_dw    = (const float*)d_in[9];
  const float* g_dw    = (const float*)d_in[10];
  const float* be_dw   = (const float*)d_in[11];
  const float* w_pw    = (const float*)d_in[12];
  const float* g_pw    = (const float*)d_in[13];
  const float* be_pw   = (const float*)d_in[14];
  float* out = (float*)d_out;

  float* ws    = (float*)d_ws;
  float* xd    = ws;                       // 492032 = 4*128*961
  float* o1    = xd + 492032;              // 492032
  int*   topk  = (int*)(o1 + 492032);      // 15360 = 4*16*240
  float* yacc  = (float*)(topk + 15360);   // 984064 = 4*64*62*62
  float* z1    = yacc + 984064;            // 984064 (aliases rowstat+coarse pre-dwconv)
  float* z2    = z1 + 984064;              // 984064 (aliases o2+coordg pre-pwconv)
  float* stats = z2 + 984064;              // 256
  float* par   = stats + 256;              // 256

  float*  rowstat = z1;                    // 4*16*961 floats
  float*  coarse  = z1 + 61504;            // 4*16*961 floats
  float4* o2      = (float4*)z2;           // 4*16*960 float4
  int*    coordg  = (int*)(z2 + 245760);   // 61440 ints

  k_zero<<<1, 256, 0, stream>>>(stats, 256);
  k_down<<<256, 256, 0, stream>>>(x, w_down, b_down, xd);
  k_attn1<<<512, 256, 0, stream>>>(xd, w_qkv_c, b_qkv_c, o1, rowstat);
  k_coarse<<<256, 256, 0, stream>>>(xd, w_qkv_c, b_qkv_c, rowstat, coarse);
  k_topk<<<64, 256, 0, stream>>>(coarse, topk);
  k_upconv<<<256, 256, 0, stream>>>(o1, w_up, b_up, yacc);
  k_attn2<<<256, 256, 0, stream>>>(yacc, w_qkv_t, b_qkv_t, topk, o2, coordg);
  k_scatter<<<(64 * N2 + 255) / 256, 256, 0, stream>>>(yacc, o2, coordg);
  k_dwconv<<<(64 * NPIX + 255) / 256, 256, 0, stream>>>(yacc, w_dw, z1);
  k_stats<<<256, 256, 0, stream>>>(z1, stats);
  k_bnparam<<<1, 64, 0, stream>>>(stats, g_dw, be_dw, par);
  k_pwconv<<<(NPIX + 255) / 256, 256, 0, stream>>>(z1, w_pw, par, z2);
  k_stats<<<256, 256, 0, stream>>>(z2, stats + 128);
  k_bnparam<<<1, 64, 0, stream>>>(stats + 128, g_pw, be_pw, par + 128);
  k_final<<<(64 * NPIX + 255) / 256, 256, 0, stream>>>(z2, par + 128, out);
}

// Round 5
// 407.563 us; speedup vs baseline: 2.3389x; 1.0476x over previous
//
#include <hip/hip_runtime.h>
#include <math.h>

#define N1 961
#define N2 960
#define KF 240
#define HW2 3844   // 62*62
#define NPIX 15376 // 4*62*62

__global__ void k_zero(float* p, int n) {
  int i = blockIdx.x * 256 + threadIdx.x;
  if (i < n) p[i] = 0.f;
}

// down conv, wave-uniform weights: x(4,64,64,64)*w(128,64,4,4) s2 -> xd(4,128,31,31)
// grid 512 = b(4) x cog(8: 16 co) x tile(16: 8x8 px). wave = 4 co x 64 px -> scalar weight loads.
__global__ __launch_bounds__(256) void k_down(const float* __restrict__ x,
                                              const float* __restrict__ w,
                                              const float* __restrict__ bias,
                                              float* __restrict__ xd) {
  __shared__ float iS[8][18][20];
  int tid = threadIdx.x;
  int bid = blockIdx.x;
  int b = bid >> 7;
  int cog = (bid >> 4) & 7;
  int tile = bid & 15;
  int r0 = (tile >> 2) * 8, c0 = (tile & 3) * 8;
  int wv = __builtin_amdgcn_readfirstlane(tid >> 6);
  int lane = tid & 63;
  int pr = lane >> 3, pc = lane & 7;
  int cobase = cog * 16 + wv * 4;
  float acc[4] = {0.f, 0.f, 0.f, 0.f};
  const float* xb = x + (size_t)b * 64 * 4096;
  for (int ch = 0; ch < 8; ch++) {
    __syncthreads();
    for (int e = tid; e < 8 * 18 * 18; e += 256) {
      int dx = e % 18; int t = e / 18;
      int dy = t % 18; int ci = t / 18;
      int iy = 2 * r0 + dy, ix = 2 * c0 + dx;
      float v = (iy < 64 && ix < 64) ? xb[(size_t)(ch * 8 + ci) * 4096 + iy * 64 + ix] : 0.f;
      iS[ci][dy][dx] = v;
    }
    __syncthreads();
    for (int ci = 0; ci < 8; ci++) {
      float xr[4][4];
      #pragma unroll
      for (int ky = 0; ky < 4; ky++) {
        const float2* rp = (const float2*)&iS[ci][2 * pr + ky][2 * pc];
        float2 a = rp[0], bb = rp[1];
        xr[ky][0] = a.x; xr[ky][1] = a.y; xr[ky][2] = bb.x; xr[ky][3] = bb.y;
      }
      int cig = ch * 8 + ci;
      #pragma unroll
      for (int cc = 0; cc < 4; cc++) {
        const float* wp = w + (size_t)(cobase + cc) * 1024 + cig * 16;  // wave-uniform -> s_load
        #pragma unroll
        for (int ky = 0; ky < 4; ky++)
          #pragma unroll
          for (int kx = 0; kx < 4; kx++)
            acc[cc] += xr[ky][kx] * wp[ky * 4 + kx];
      }
    }
  }
  int i = r0 + pr, j = c0 + pc;
  if (i >= 31 || j >= 31) return;
  #pragma unroll
  for (int cc = 0; cc < 4; cc++)
    xd[(size_t)(b * 128 + cobase + cc) * N1 + i * 31 + j] = acc[cc] + bias[cobase + cc];
}

#define QKV_EXPR(off) make_float4( \
    t0 * Ws[(off)] + t1 * Ws[12 + (off)] + t2 * Ws[24 + (off)] + t3 * Ws[36 + (off)] + Bs[(off)], \
    t0 * Ws[(off)+1] + t1 * Ws[12 + (off)+1] + t2 * Ws[24 + (off)+1] + t3 * Ws[36 + (off)+1] + Bs[(off)+1], \
    t0 * Ws[(off)+2] + t1 * Ws[12 + (off)+2] + t2 * Ws[24 + (off)+2] + t3 * Ws[36 + (off)+2] + Bs[(off)+2], \
    t0 * Ws[(off)+3] + t1 * Ws[12 + (off)+3] + t2 * Ws[24 + (off)+3] + t3 * Ws[36 + (off)+3] + Bs[(off)+3])

// attention 1, single-pass, 2-way m-split per row. grid = 128 bg x 8 chunks of 128 rows.
// wave = 32 rows x 2 halves; shfl_xor(32) combine. rowstat = 1/sum for g<16.
__global__ __launch_bounds__(256) void k_attn1(const float* __restrict__ xd,
                                               const float* __restrict__ wqkv,
                                               const float* __restrict__ bqkv,
                                               float* __restrict__ o1,
                                               float* __restrict__ rowstat) {
  __shared__ float4 qvv[2 * N1];
  __shared__ float Ws[48], Bs[12];
  int tid = threadIdx.x;
  int chunk = blockIdx.x & 7;
  int bg = blockIdx.x >> 3;
  int b = bg >> 5, g = bg & 31;
  if (tid < 48) Ws[tid] = wqkv[tid];
  if (tid < 12) Bs[tid] = bqkv[tid];
  __syncthreads();
  const float* xp0 = xd + (size_t)(b * 128 + g * 4) * N1;
  for (int nn = tid; nn < N1; nn += 256) {
    float t0 = xp0[nn], t1 = xp0[N1 + nn], t2 = xp0[2 * N1 + nn], t3 = xp0[3 * N1 + nn];
    qvv[2 * nn]     = QKV_EXPR(0);
    qvv[2 * nn + 1] = QKV_EXPR(8);
  }
  __syncthreads();
  int wv = tid >> 6, lane = tid & 63;
  int half = lane >> 5;
  int n = chunk * 128 + wv * 32 + (lane & 31);
  if (n >= N1) return;  // partner half shares n -> exits together
  float t0 = xp0[n], t1 = xp0[N1 + n], t2 = xp0[2 * N1 + n], t3 = xp0[3 * N1 + n];
  float4 kr = QKV_EXPR(4);
  int mstart = half * 481;
  int mend = half ? N1 : 481;
  float sum = 0.f, a0 = 0.f, a1 = 0.f, a2 = 0.f, a3 = 0.f;
  #pragma unroll 4
  for (int m = mstart; m < mend; m++) {
    float4 q = qvv[2 * m];
    float4 v = qvv[2 * m + 1];
    float s = kr.x * q.x + kr.y * q.y + kr.z * q.z + kr.w * q.w;
    float e = __expf(s);
    sum += e;
    a0 += e * v.x; a1 += e * v.y; a2 += e * v.z; a3 += e * v.w;
  }
  sum += __shfl_xor(sum, 32, 64);
  a0 += __shfl_xor(a0, 32, 64);
  a1 += __shfl_xor(a1, 32, 64);
  a2 += __shfl_xor(a2, 32, 64);
  a3 += __shfl_xor(a3, 32, 64);
  if (half) return;
  float inv = 1.0f / sum;
  float* o1p = o1 + (size_t)(b * 128 + g * 4) * N1;
  o1p[n] = a0 * inv;
  o1p[N1 + n] = a1 * inv;
  o1p[2 * N1 + n] = a2 * inv;
  o1p[3 * N1 + n] = a3 * inv;
  if (g < 16) rowstat[(size_t)(b * 16 + g) * N1 + n] = inv;
}

// coarse[m] = sum_n exp(s[n,m])*inv_n; 4-way n-split per column.
// grid = 64 bg x 16 chunks of 64 cols; wave = 16 cols x 4 quarters.
__global__ __launch_bounds__(256) void k_coarse(const float* __restrict__ xd,
                                                const float* __restrict__ wqkv,
                                                const float* __restrict__ bqkv,
                                                const float* __restrict__ rowstat,
                                                float* __restrict__ coarse) {
  __shared__ float4 kS[N1];
  __shared__ float rs[N1];
  __shared__ float Ws[48], Bs[12];
  int tid = threadIdx.x;
  int chunk = blockIdx.x & 15;
  int bg = blockIdx.x >> 4;
  int b = bg >> 4, g = bg & 15;
  if (tid < 48) Ws[tid] = wqkv[tid];
  if (tid < 12) Bs[tid] = bqkv[tid];
  __syncthreads();
  const float* xp0 = xd + (size_t)(b * 128 + g * 4) * N1;
  const float* rp = rowstat + (size_t)(b * 16 + g) * N1;
  for (int nn = tid; nn < N1; nn += 256) {
    float t0 = xp0[nn], t1 = xp0[N1 + nn], t2 = xp0[2 * N1 + nn], t3 = xp0[3 * N1 + nn];
    kS[nn] = QKV_EXPR(4);
    rs[nn] = rp[nn];
  }
  __syncthreads();
  int wv = tid >> 6, lane = tid & 63;
  int q4 = lane >> 4;
  int m = chunk * 64 + wv * 16 + (lane & 15);
  if (m >= N1) return;  // all quarters share m -> exit together
  float t0 = xp0[m], t1 = xp0[N1 + m], t2 = xp0[2 * N1 + m], t3 = xp0[3 * N1 + m];
  float4 q = QKV_EXPR(0);
  int ns = q4 * 241;
  int ne = (ns + 241 < N1) ? ns + 241 : N1;
  float c = 0.f;
  #pragma unroll 4
  for (int n = ns; n < ne; n++) {
    float4 k = kS[n];
    float s = k.x * q.x + k.y * q.y + k.z * q.z + k.w * q.w;
    c += __expf(s) * rs[n];
  }
  c += __shfl_xor(c, 16, 64);
  c += __shfl_xor(c, 32, 64);
  if (q4 == 0) coarse[(size_t)(b * 16 + g) * N1 + m] = c;
}

// top-240 per (b,g<16): bitonic over 1024 packed keys
__global__ __launch_bounds__(256) void k_topk(const float* __restrict__ coarse,
                                              int* __restrict__ topk) {
  __shared__ unsigned long long keys[1024];
  int tid = threadIdx.x;
  int bg = blockIdx.x;
  const float* cp = coarse + (size_t)bg * N1;
  for (int i = tid; i < 1024; i += 256) {
    unsigned long long key = 0ull;
    if (i < N1) {
      unsigned fb = __float_as_uint(cp[i]);
      key = ((unsigned long long)fb << 32) | (unsigned)(N1 - 1 - i);
    }
    keys[i] = key;
  }
  __syncthreads();
  for (int k2 = 2; k2 <= 1024; k2 <<= 1) {
    for (int j = k2 >> 1; j > 0; j >>= 1) {
      for (int i = tid; i < 1024; i += 256) {
        int ixj = i ^ j;
        if (ixj > i) {
          unsigned long long a = keys[i], bb = keys[ixj];
          bool up = ((i & k2) == 0);
          if ((a > bb) == up) { keys[i] = bb; keys[ixj] = a; }
        }
      }
      __syncthreads();
    }
  }
  if (tid < KF) {
    unsigned long long key = keys[1023 - tid];
    topk[(size_t)bg * KF + tid] = (N1 - 1) - (int)(unsigned)(key & 0xffffffffull);
  }
}

// transposed conv, per-parity, wave-uniform weights: o1(4,128,31,31) -> yacc = 2*coarse_out
// grid 1024 = b(4) x cog(4: 16 co) x parity(4) x tile(16: 8x8 px in 31x31 parity space)
__global__ __launch_bounds__(256) void k_upconv(const float* __restrict__ o1,
                                                const float* __restrict__ w,
                                                const float* __restrict__ bias,
                                                float* __restrict__ yacc) {
  __shared__ float iS[16][9][10];
  int tid = threadIdx.x;
  int bid = blockIdx.x;
  int b = bid >> 8;
  int cog = (bid >> 6) & 3;
  int par = (bid >> 4) & 3;
  int py = par >> 1, px = par & 1;
  int tile = bid & 15;
  int r0 = (tile >> 2) * 8, c0 = (tile & 3) * 8;
  int wv = __builtin_amdgcn_readfirstlane(tid >> 6);
  int lane = tid & 63;
  int pr = lane >> 3, pc = lane & 7;
  int cobase = cog * 16 + wv * 4;
  int wo[4];
  #pragma unroll
  for (int t = 0; t < 4; t++) {
    int a = t >> 1, d = t & 1;
    wo[t] = (3 - (py + 2 * a)) * 4 + (3 - (px + 2 * d));
  }
  float acc[4] = {0.f, 0.f, 0.f, 0.f};
  const float* ob = o1 + (size_t)b * 128 * N1;
  for (int ch = 0; ch < 8; ch++) {
    __syncthreads();
    for (int e = tid; e < 16 * 81; e += 256) {
      int dx = e % 9; int t = e / 9;
      int dy = t % 9; int ci = t / 9;
      int iy = r0 + py - 1 + dy, ix = c0 + px - 1 + dx;
      float v = 0.f;
      if (iy >= 0 && iy < 31 && ix >= 0 && ix < 31)
        v = ob[(size_t)(ch * 16 + ci) * N1 + iy * 31 + ix];
      iS[ci][dy][dx] = v;
    }
    __syncthreads();
    for (int ci = 0; ci < 16; ci++) {
      float xr[2][2];
      #pragma unroll
      for (int a = 0; a < 2; a++) {
        xr[a][0] = iS[ci][pr + a][pc];
        xr[a][1] = iS[ci][pr + a][pc + 1];
      }
      int cig = ch * 16 + ci;
      #pragma unroll
      for (int cc = 0; cc < 4; cc++) {
        const float* wp = w + (size_t)cig * 1024 + (cobase + cc) * 16;  // wave-uniform
        #pragma unroll
        for (int t = 0; t < 4; t++)
          acc[cc] += xr[t >> 1][t & 1] * wp[wo[t]];
      }
    }
  }
  int r = r0 + pr, c = c0 + pc;
  if (r >= 31 || c >= 31) return;
  int y = 2 * r + py, xx = 2 * c + px;
  #pragma unroll
  for (int cc = 0; cc < 4; cc++) {
    int co = cobase + cc;
    yacc[(size_t)(b * 64 + co) * HW2 + y * 62 + xx] = 2.0f * (acc[cc] + bias[co]);
  }
}

// attention 2, single-pass, 2-way m-split. grid = 64 bg x 8 chunks of 128 rows.
__global__ __launch_bounds__(256) void k_attn2(const float* __restrict__ yacc,
                                               const float* __restrict__ wqkv,
                                               const float* __restrict__ bqkv,
                                               const int* __restrict__ topk,
                                               float4* __restrict__ o2,
                                               int* __restrict__ coordg) {
  __shared__ float4 qvv[2 * N2];
  __shared__ float Ws[48], Bs[12];
  int tid = threadIdx.x;
  int chunk = blockIdx.x & 7;
  int bg = blockIdx.x >> 3;
  int b = bg >> 4, g = bg & 15;
  if (tid < 48) Ws[tid] = wqkv[tid];
  if (tid < 12) Bs[tid] = bqkv[tid];
  __syncthreads();
  const float* yp0 = yacc + (size_t)(b * 64 + g * 4) * HW2;
  const int* ip = topk + (size_t)bg * KF;
  for (int nn = tid; nn < N2; nn += 256) {
    int tt = nn >> 2, i = (nn >> 1) & 1, j = nn & 1;
    int p = ip[tt];
    int ph = p / 31, pw = p - ph * 31;
    int cc = (2 * ph + i) * 62 + (2 * pw + j);
    float t0 = 0.5f * yp0[cc], t1 = 0.5f * yp0[HW2 + cc];
    float t2 = 0.5f * yp0[2 * HW2 + cc], t3 = 0.5f * yp0[3 * HW2 + cc];
    qvv[2 * nn]     = QKV_EXPR(0);
    qvv[2 * nn + 1] = QKV_EXPR(8);
  }
  __syncthreads();
  int wv = tid >> 6, lane = tid & 63;
  int half = lane >> 5;
  int n = chunk * 128 + wv * 32 + (lane & 31);
  if (n >= N2) return;
  int tt = n >> 2, i = (n >> 1) & 1, j = n & 1;
  int p = ip[tt];
  int ph = p / 31, pw = p - ph * 31;
  int cc = (2 * ph + i) * 62 + (2 * pw + j);
  float t0 = 0.5f * yp0[cc], t1 = 0.5f * yp0[HW2 + cc];
  float t2 = 0.5f * yp0[2 * HW2 + cc], t3 = 0.5f * yp0[3 * HW2 + cc];
  float4 kr = QKV_EXPR(4);
  int mstart = half * 481;
  int mend = half ? N2 : 481;
  float sum = 0.f, a0 = 0.f, a1 = 0.f, a2 = 0.f, a3 = 0.f;
  #pragma unroll 4
  for (int m = mstart; m < mend; m++) {
    float4 q = qvv[2 * m];
    float4 v = qvv[2 * m + 1];
    float s = kr.x * q.x + kr.y * q.y + kr.z * q.z + kr.w * q.w;
    float e = __expf(s);
    sum += e;
    a0 += e * v.x; a1 += e * v.y; a2 += e * v.z; a3 += e * v.w;
  }
  sum += __shfl_xor(sum, 32, 64);
  a0 += __shfl_xor(a0, 32, 64);
  a1 += __shfl_xor(a1, 32, 64);
  a2 += __shfl_xor(a2, 32, 64);
  a3 += __shfl_xor(a3, 32, 64);
  if (half) return;
  float inv = 1.0f / sum;
  size_t oi = (size_t)bg * N2 + n;
  o2[oi] = make_float4(a0 * inv, a1 * inv, a2 * inv, a3 * inv);
  coordg[oi] = cc;
}

// scatter-add attn2 output into yacc (disjoint targets)
__global__ __launch_bounds__(256) void k_scatter(float* __restrict__ yacc,
                                                 const float4* __restrict__ o2,
                                                 const int* __restrict__ coordg) {
  int idx = blockIdx.x * 256 + threadIdx.x;
  if (idx >= 64 * N2) return;
  int bg = idx / N2;
  int b = bg >> 4, g = bg & 15;
  float4 o = o2[idx];
  int cc = coordg[idx];
  float* yp0 = yacc + (size_t)(b * 64 + g * 4) * HW2;
  yp0[cc] += o.x;
  yp0[HW2 + cc] += o.y;
  yp0[2 * HW2 + cc] += o.z;
  yp0[3 * HW2 + cc] += o.w;
}

// depthwise 3x3, pad 1
__global__ __launch_bounds__(256) void k_dwconv(const float* __restrict__ yin,
                                                const float* __restrict__ w,
                                                float* __restrict__ z1) {
  int idx = blockIdx.x * 256 + threadIdx.x;
  if (idx >= 64 * NPIX) return;
  int x = idx % 62; int t = idx / 62;
  int y = t % 62; t /= 62;
  int c = t % 64;
  int plane = idx / HW2;
  const float* yp = yin + (size_t)plane * HW2;
  const float* wp = w + c * 9;
  float acc = 0.f;
  #pragma unroll
  for (int ky = 0; ky < 3; ky++) {
    int yy = y + ky - 1;
    if (yy < 0 || yy > 61) continue;
    #pragma unroll
    for (int kx = 0; kx < 3; kx++) {
      int xx = x + kx - 1;
      if (xx < 0 || xx > 61) continue;
      acc += yp[yy * 62 + xx] * wp[ky * 3 + kx];
    }
  }
  z1[idx] = acc;
}

__device__ __forceinline__ float wave_sum(float x) {
  #pragma unroll
  for (int off = 32; off > 0; off >>= 1) x += __shfl_xor(x, off, 64);
  return x;
}

__global__ __launch_bounds__(256) void k_stats(const float* __restrict__ buf,
                                               float* __restrict__ stats) {
  __shared__ float red[8];
  int c = blockIdx.x >> 2, b = blockIdx.x & 3;
  const float* p = buf + (size_t)(b * 64 + c) * HW2;
  float s = 0.f, s2 = 0.f;
  for (int i = threadIdx.x; i < HW2; i += 256) { float z = p[i]; s += z; s2 += z * z; }
  s = wave_sum(s); s2 = wave_sum(s2);
  int wave = threadIdx.x >> 6, lane = threadIdx.x & 63;
  if (lane == 0) { red[wave] = s; red[4 + wave] = s2; }
  __syncthreads();
  if (threadIdx.x == 0) {
    atomicAdd(&stats[c], red[0] + red[1] + red[2] + red[3]);
    atomicAdd(&stats[64 + c], red[4] + red[5] + red[6] + red[7]);
  }
}

__global__ void k_bnparam(const float* __restrict__ stats, const float* __restrict__ gamma,
                          const float* __restrict__ beta, float* __restrict__ par) {
  int c = threadIdx.x;
  if (c < 64) {
    float m = stats[c] * (1.0f / NPIX);
    float v = stats[64 + c] * (1.0f / NPIX) - m * m;
    float a = gamma[c] * rsqrtf(v + 1e-5f);
    par[c] = a; par[64 + c] = beta[c] - m * a;
  }
}

// pointwise 1x1, co-split x4: grid = pixblocks(61) x cog(4: 16 co)
__global__ __launch_bounds__(256) void k_pwconv(const float* __restrict__ z1,
                                                const float* __restrict__ wpw,
                                                const float* __restrict__ par,
                                                float* __restrict__ z2) {
  __shared__ float w[16 * 64];
  __shared__ float aa[64], cb[64];
  int tid = threadIdx.x;
  int cog = blockIdx.x & 3;
  int pb = blockIdx.x >> 2;
  for (int i = tid; i < 1024; i += 256) w[i] = wpw[cog * 1024 + i];
  if (tid < 64) { aa[tid] = par[tid]; cb[tid] = par[64 + tid]; }
  __syncthreads();
  int pix = pb * 256 + tid;
  if (pix >= NPIX) return;
  int b = pix / HW2, p = pix - b * HW2;
  float h[64];
  #pragma unroll
  for (int ci = 0; ci < 64; ci++) {
    float z = z1[(size_t)(b * 64 + ci) * HW2 + p];
    z = aa[ci] * z + cb[ci];
    h[ci] = fminf(fmaxf(z, 0.f), 6.f);
  }
  #pragma unroll
  for (int cc = 0; cc < 16; cc++) {
    float acc = 0.f;
    #pragma unroll
    for (int ci = 0; ci < 64; ci++) acc += h[ci] * w[cc * 64 + ci];
    z2[(size_t)(b * 64 + cog * 16 + cc) * HW2 + p] = acc;
  }
}

__global__ __launch_bounds__(256) void k_final(const float* __restrict__ z2,
                                               const float* __restrict__ par,
                                               float* __restrict__ out) {
  int idx = blockIdx.x * 256 + threadIdx.x;
  if (idx >= 64 * NPIX) return;
  int c = (idx / HW2) & 63;
  float z = par[c] * z2[idx] + par[64 + c];
  out[idx] = fminf(fmaxf(z, 0.f), 6.f);
}

extern "C" void kernel_launch(void* const* d_in, const int* in_sizes, int n_in,
                              void* d_out, int out_size, void* d_ws, size_t ws_size,
                              hipStream_t stream) {
  const float* x       = (const float*)d_in[0];
  const float* w_down  = (const float*)d_in[1];
  const float* b_down  = (const float*)d_in[2];
  const float* w_qkv_c = (const float*)d_in[3];
  const float* b_qkv_c = (const float*)d_in[4];
  const float* w_up    = (const float*)d_in[5];
  const float* b_up    = (const float*)d_in[6];
  const float* w_qkv_t = (const float*)d_in[7];
  const float* b_qkv_t = (const float*)d_in[8];
  const float* w_dw    = (const float*)d_in[9];
  const float* g_dw    = (const float*)d_in[10];
  const float* be_dw   = (const float*)d_in[11];
  const float* w_pw    = (const float*)d_in[12];
  const float* g_pw    = (const float*)d_in[13];
  const float* be_pw   = (const float*)d_in[14];
  float* out = (float*)d_out;

  float* ws    = (float*)d_ws;
  float* xd    = ws;                       // 492032 = 4*128*961
  float* o1    = xd + 492032;              // 492032
  int*   topk  = (int*)(o1 + 492032);      // 15360 = 4*16*240
  float* yacc  = (float*)(topk + 15360);   // 984064 = 4*64*62*62
  float* z1    = yacc + 984064;            // 984064 (aliases rowstat+coarse pre-dwconv)
  float* z2    = z1 + 984064;              // 984064 (aliases o2+coordg pre-pwconv)
  float* stats = z2 + 984064;              // 256
  float* par   = stats + 256;              // 256

  float*  rowstat = z1;                    // 4*16*961 floats
  float*  coarse  = z1 + 61504;            // 4*16*961 floats
  float4* o2      = (float4*)z2;           // 4*16*960 float4
  int*    coordg  = (int*)(z2 + 245760);   // 61440 ints

  k_zero<<<1, 256, 0, stream>>>(stats, 256);
  k_down<<<512, 256, 0, stream>>>(x, w_down, b_down, xd);
  k_attn1<<<1024, 256, 0, stream>>>(xd, w_qkv_c, b_qkv_c, o1, rowstat);
  k_coarse<<<1024, 256, 0, stream>>>(xd, w_qkv_c, b_qkv_c, rowstat, coarse);
  k_topk<<<64, 256, 0, stream>>>(coarse, topk);
  k_upconv<<<1024, 256, 0, stream>>>(o1, w_up, b_up, yacc);
  k_attn2<<<512, 256, 0, stream>>>(yacc, w_qkv_t, b_qkv_t, topk, o2, coordg);
  k_scatter<<<(64 * N2 + 255) / 256, 256, 0, stream>>>(yacc, o2, coordg);
  k_dwconv<<<(64 * NPIX + 255) / 256, 256, 0, stream>>>(yacc, w_dw, z1);
  k_stats<<<256, 256, 0, stream>>>(z1, stats);
  k_bnparam<<<1, 64, 0, stream>>>(stats, g_dw, be_dw, par);
  k_pwconv<<<244, 256, 0, stream>>>(z1, w_pw, par, z2);
  k_stats<<<256, 256, 0, stream>>>(z2, stats + 128);
  k_bnparam<<<1, 64, 0, stream>>>(stats + 128, g_pw, be_pw, par + 128);
  k_final<<<(64 * NPIX + 255) / 256, 256, 0, stream>>>(z2, par + 128, out);
}

// Round 6
// 394.645 us; speedup vs baseline: 2.4154x; 1.0327x over previous
//
#include <hip/hip_runtime.h>
#include <math.h>

#define N1 961
#define N2 960
#define KF 240
#define HW2 3844   // 62*62
#define NPIX 15376 // 4*62*62

__global__ void k_zero(float* p, int n) {
  int i = blockIdx.x * 256 + threadIdx.x;
  if (i < n) p[i] = 0.f;
}

// down conv: x(4,64,64,64)*w(128,64,4,4) s2 -> xd(4,128,31,31)
// grid 512 = b(4) x cog(8: 16 co) x tile(16: 4x4 of 8x8 px).
// wave = 4 co x 64 px; weights staged in LDS, read as wave-uniform b128 broadcasts.
__global__ __launch_bounds__(256) void k_down(const float* __restrict__ x,
                                              const float* __restrict__ w,
                                              const float* __restrict__ bias,
                                              float* __restrict__ xd) {
  __shared__ float iS[8][18][20];
  __shared__ float wS[8][16][16];  // [ci][tap][co16]
  int tid = threadIdx.x;
  int bid = blockIdx.x;
  int b = bid >> 7;
  int cog = (bid >> 4) & 7;
  int tile = bid & 15;
  int r0 = (tile >> 2) * 8, c0 = (tile & 3) * 8;
  int wv = tid >> 6, lane = tid & 63;
  int pr = lane >> 3, pc = lane & 7;
  int cobase = cog * 16 + wv * 4;
  float acc[4] = {0.f, 0.f, 0.f, 0.f};
  const float* xb = x + (size_t)b * 64 * 4096;
  const float* wb = w + (size_t)cog * 16 * 1024;
  for (int ch = 0; ch < 8; ch++) {
    __syncthreads();
    for (int e = tid; e < 8 * 18 * 18; e += 256) {
      int dx = e % 18; int t = e / 18;
      int dy = t % 18; int ci = t / 18;
      int iy = 2 * r0 + dy, ix = 2 * c0 + dx;
      iS[ci][dy][dx] = (iy < 64 && ix < 64) ? xb[(size_t)(ch * 8 + ci) * 4096 + iy * 64 + ix] : 0.f;
    }
    for (int e = tid; e < 2048; e += 256) {
      int co = e & 15, tap = (e >> 4) & 15, ci = e >> 8;
      wS[ci][tap][co] = wb[(size_t)co * 1024 + (ch * 8 + ci) * 16 + tap];
    }
    __syncthreads();
    #pragma unroll
    for (int ci = 0; ci < 8; ci++) {
      float xr[4][4];
      #pragma unroll
      for (int ky = 0; ky < 4; ky++) {
        float2 a2 = *(const float2*)&iS[ci][2 * pr + ky][2 * pc];
        float2 b2 = *(const float2*)&iS[ci][2 * pr + ky][2 * pc + 2];
        xr[ky][0] = a2.x; xr[ky][1] = a2.y; xr[ky][2] = b2.x; xr[ky][3] = b2.y;
      }
      #pragma unroll
      for (int ky = 0; ky < 4; ky++)
        #pragma unroll
        for (int kx = 0; kx < 4; kx++) {
          float4 wq = *(const float4*)&wS[ci][ky * 4 + kx][wv * 4];  // broadcast
          float xv = xr[ky][kx];
          acc[0] += wq.x * xv; acc[1] += wq.y * xv;
          acc[2] += wq.z * xv; acc[3] += wq.w * xv;
        }
    }
  }
  int i = r0 + pr, j = c0 + pc;
  if (i >= 31 || j >= 31) return;
  #pragma unroll
  for (int cc = 0; cc < 4; cc++)
    xd[(size_t)(b * 128 + cobase + cc) * N1 + i * 31 + j] = acc[cc] + bias[cobase + cc];
}

#define QKV_EXPR(off) make_float4( \
    t0 * Ws[(off)] + t1 * Ws[12 + (off)] + t2 * Ws[24 + (off)] + t3 * Ws[36 + (off)] + Bs[(off)], \
    t0 * Ws[(off)+1] + t1 * Ws[12 + (off)+1] + t2 * Ws[24 + (off)+1] + t3 * Ws[36 + (off)+1] + Bs[(off)+1], \
    t0 * Ws[(off)+2] + t1 * Ws[12 + (off)+2] + t2 * Ws[24 + (off)+2] + t3 * Ws[36 + (off)+2] + Bs[(off)+2], \
    t0 * Ws[(off)+3] + t1 * Ws[12 + (off)+3] + t2 * Ws[24 + (off)+3] + t3 * Ws[36 + (off)+3] + Bs[(off)+3])

// attention 1, single-pass, 2-way m-split per row. grid = 128 bg x 8 chunks of 128 rows.
__global__ __launch_bounds__(256) void k_attn1(const float* __restrict__ xd,
                                               const float* __restrict__ wqkv,
                                               const float* __restrict__ bqkv,
                                               float* __restrict__ o1,
                                               float* __restrict__ rowstat) {
  __shared__ float4 qvv[2 * N1];
  __shared__ float Ws[48], Bs[12];
  int tid = threadIdx.x;
  int chunk = blockIdx.x & 7;
  int bg = blockIdx.x >> 3;
  int b = bg >> 5, g = bg & 31;
  if (tid < 48) Ws[tid] = wqkv[tid];
  if (tid < 12) Bs[tid] = bqkv[tid];
  __syncthreads();
  const float* xp0 = xd + (size_t)(b * 128 + g * 4) * N1;
  for (int nn = tid; nn < N1; nn += 256) {
    float t0 = xp0[nn], t1 = xp0[N1 + nn], t2 = xp0[2 * N1 + nn], t3 = xp0[3 * N1 + nn];
    qvv[2 * nn]     = QKV_EXPR(0);
    qvv[2 * nn + 1] = QKV_EXPR(8);
  }
  __syncthreads();
  int wv = tid >> 6, lane = tid & 63;
  int half = lane >> 5;
  int n = chunk * 128 + wv * 32 + (lane & 31);
  if (n >= N1) return;
  float t0 = xp0[n], t1 = xp0[N1 + n], t2 = xp0[2 * N1 + n], t3 = xp0[3 * N1 + n];
  float4 kr = QKV_EXPR(4);
  int mstart = half * 481;
  int mend = half ? N1 : 481;
  float sum = 0.f, a0 = 0.f, a1 = 0.f, a2 = 0.f, a3 = 0.f;
  #pragma unroll 4
  for (int m = mstart; m < mend; m++) {
    float4 q = qvv[2 * m];
    float4 v = qvv[2 * m + 1];
    float s = kr.x * q.x + kr.y * q.y + kr.z * q.z + kr.w * q.w;
    float e = __expf(s);
    sum += e;
    a0 += e * v.x; a1 += e * v.y; a2 += e * v.z; a3 += e * v.w;
  }
  sum += __shfl_xor(sum, 32, 64);
  a0 += __shfl_xor(a0, 32, 64);
  a1 += __shfl_xor(a1, 32, 64);
  a2 += __shfl_xor(a2, 32, 64);
  a3 += __shfl_xor(a3, 32, 64);
  if (half) return;
  float inv = 1.0f / sum;
  float* o1p = o1 + (size_t)(b * 128 + g * 4) * N1;
  o1p[n] = a0 * inv;
  o1p[N1 + n] = a1 * inv;
  o1p[2 * N1 + n] = a2 * inv;
  o1p[3 * N1 + n] = a3 * inv;
  if (g < 16) rowstat[(size_t)(b * 16 + g) * N1 + n] = inv;
}

// coarse[m] = sum_n exp(s[n,m])*inv_n; 4-way n-split per column.
__global__ __launch_bounds__(256) void k_coarse(const float* __restrict__ xd,
                                                const float* __restrict__ wqkv,
                                                const float* __restrict__ bqkv,
                                                const float* __restrict__ rowstat,
                                                float* __restrict__ coarse) {
  __shared__ float4 kS[N1];
  __shared__ float rs[N1];
  __shared__ float Ws[48], Bs[12];
  int tid = threadIdx.x;
  int chunk = blockIdx.x & 15;
  int bg = blockIdx.x >> 4;
  int b = bg >> 4, g = bg & 15;
  if (tid < 48) Ws[tid] = wqkv[tid];
  if (tid < 12) Bs[tid] = bqkv[tid];
  __syncthreads();
  const float* xp0 = xd + (size_t)(b * 128 + g * 4) * N1;
  const float* rp = rowstat + (size_t)(b * 16 + g) * N1;
  for (int nn = tid; nn < N1; nn += 256) {
    float t0 = xp0[nn], t1 = xp0[N1 + nn], t2 = xp0[2 * N1 + nn], t3 = xp0[3 * N1 + nn];
    kS[nn] = QKV_EXPR(4);
    rs[nn] = rp[nn];
  }
  __syncthreads();
  int wv = tid >> 6, lane = tid & 63;
  int q4 = lane >> 4;
  int m = chunk * 64 + wv * 16 + (lane & 15);
  if (m >= N1) return;
  float t0 = xp0[m], t1 = xp0[N1 + m], t2 = xp0[2 * N1 + m], t3 = xp0[3 * N1 + m];
  float4 q = QKV_EXPR(0);
  int ns = q4 * 241;
  int ne = (ns + 241 < N1) ? ns + 241 : N1;
  float c = 0.f;
  #pragma unroll 4
  for (int n = ns; n < ne; n++) {
    float4 k = kS[n];
    float s = k.x * q.x + k.y * q.y + k.z * q.z + k.w * q.w;
    c += __expf(s) * rs[n];
  }
  c += __shfl_xor(c, 16, 64);
  c += __shfl_xor(c, 32, 64);
  if (q4 == 0) coarse[(size_t)(b * 16 + g) * N1 + m] = c;
}

// top-240 per (b,g<16): bitonic over 1024 packed keys
__global__ __launch_bounds__(256) void k_topk(const float* __restrict__ coarse,
                                              int* __restrict__ topk) {
  __shared__ unsigned long long keys[1024];
  int tid = threadIdx.x;
  int bg = blockIdx.x;
  const float* cp = coarse + (size_t)bg * N1;
  for (int i = tid; i < 1024; i += 256) {
    unsigned long long key = 0ull;
    if (i < N1) {
      unsigned fb = __float_as_uint(cp[i]);
      key = ((unsigned long long)fb << 32) | (unsigned)(N1 - 1 - i);
    }
    keys[i] = key;
  }
  __syncthreads();
  for (int k2 = 2; k2 <= 1024; k2 <<= 1) {
    for (int j = k2 >> 1; j > 0; j >>= 1) {
      for (int i = tid; i < 1024; i += 256) {
        int ixj = i ^ j;
        if (ixj > i) {
          unsigned long long a = keys[i], bb = keys[ixj];
          bool up = ((i & k2) == 0);
          if ((a > bb) == up) { keys[i] = bb; keys[ixj] = a; }
        }
      }
      __syncthreads();
    }
  }
  if (tid < KF) {
    unsigned long long key = keys[1023 - tid];
    topk[(size_t)bg * KF + tid] = (N1 - 1) - (int)(unsigned)(key & 0xffffffffull);
  }
}

// transposed conv, per-parity: o1(4,128,31,31) -> yacc = 2*coarse_out (4,64,62,62)
// grid 1024 = b(4) x cog(4: 16co) x parity(4) x tile(16). LDS-broadcast weights.
__global__ __launch_bounds__(256) void k_upconv(const float* __restrict__ o1,
                                                const float* __restrict__ w,
                                                const float* __restrict__ bias,
                                                float* __restrict__ yacc) {
  __shared__ float iS[16][9][12];
  __shared__ float wS[16][4][16];  // [ci][tap][co16]
  int tid = threadIdx.x;
  int bid = blockIdx.x;
  int b = bid >> 8;
  int cog = (bid >> 6) & 3;
  int par = (bid >> 4) & 3;
  int py = par >> 1, px = par & 1;
  int tile = bid & 15;
  int r0 = (tile >> 2) * 8, c0 = (tile & 3) * 8;
  int wv = tid >> 6, lane = tid & 63;
  int pr = lane >> 3, pc = lane & 7;
  int cobase = cog * 16 + wv * 4;
  int wo[4];
  #pragma unroll
  for (int t = 0; t < 4; t++) {
    int a = t >> 1, d = t & 1;
    wo[t] = (3 - (py + 2 * a)) * 4 + (3 - (px + 2 * d));
  }
  float acc[4] = {0.f, 0.f, 0.f, 0.f};
  const float* ob = o1 + (size_t)b * 128 * N1;
  for (int ch = 0; ch < 8; ch++) {
    __syncthreads();
    for (int e = tid; e < 16 * 81; e += 256) {
      int dx = e % 9; int t = e / 9;
      int dy = t % 9; int ci = t / 9;
      int iy = r0 + py - 1 + dy, ix = c0 + px - 1 + dx;
      float v = 0.f;
      if (iy >= 0 && iy < 31 && ix >= 0 && ix < 31)
        v = ob[(size_t)(ch * 16 + ci) * N1 + iy * 31 + ix];
      iS[ci][dy][dx] = v;
    }
    for (int e = tid; e < 1024; e += 256) {
      int co = e & 15, tap = (e >> 4) & 3, ci = e >> 6;
      wS[ci][tap][co] = w[(size_t)(ch * 16 + ci) * 1024 + (cog * 16 + co) * 16 + wo[tap]];
    }
    __syncthreads();
    #pragma unroll
    for (int ci = 0; ci < 16; ci++) {
      float xr[2][2];
      #pragma unroll
      for (int a = 0; a < 2; a++) {
        xr[a][0] = iS[ci][pr + a][pc];
        xr[a][1] = iS[ci][pr + a][pc + 1];
      }
      #pragma unroll
      for (int t = 0; t < 4; t++) {
        float4 wq = *(const float4*)&wS[ci][t][wv * 4];  // broadcast
        float xv = xr[t >> 1][t & 1];
        acc[0] += wq.x * xv; acc[1] += wq.y * xv;
        acc[2] += wq.z * xv; acc[3] += wq.w * xv;
      }
    }
  }
  int r = r0 + pr, c = c0 + pc;
  if (r >= 31 || c >= 31) return;
  int y = 2 * r + py, xx = 2 * c + px;
  #pragma unroll
  for (int cc = 0; cc < 4; cc++) {
    int co = cobase + cc;
    yacc[(size_t)(b * 64 + co) * HW2 + y * 62 + xx] = 2.0f * (acc[cc] + bias[co]);
  }
}

// attention 2, single-pass, 2-way m-split. grid = 64 bg x 8 chunks of 128 rows.
__global__ __launch_bounds__(256) void k_attn2(const float* __restrict__ yacc,
                                               const float* __restrict__ wqkv,
                                               const float* __restrict__ bqkv,
                                               const int* __restrict__ topk,
                                               float4* __restrict__ o2,
                                               int* __restrict__ coordg) {
  __shared__ float4 qvv[2 * N2];
  __shared__ float Ws[48], Bs[12];
  int tid = threadIdx.x;
  int chunk = blockIdx.x & 7;
  int bg = blockIdx.x >> 3;
  int b = bg >> 4, g = bg & 15;
  if (tid < 48) Ws[tid] = wqkv[tid];
  if (tid < 12) Bs[tid] = bqkv[tid];
  __syncthreads();
  const float* yp0 = yacc + (size_t)(b * 64 + g * 4) * HW2;
  const int* ip = topk + (size_t)bg * KF;
  for (int nn = tid; nn < N2; nn += 256) {
    int tt = nn >> 2, i = (nn >> 1) & 1, j = nn & 1;
    int p = ip[tt];
    int ph = p / 31, pw = p - ph * 31;
    int cc = (2 * ph + i) * 62 + (2 * pw + j);
    float t0 = 0.5f * yp0[cc], t1 = 0.5f * yp0[HW2 + cc];
    float t2 = 0.5f * yp0[2 * HW2 + cc], t3 = 0.5f * yp0[3 * HW2 + cc];
    qvv[2 * nn]     = QKV_EXPR(0);
    qvv[2 * nn + 1] = QKV_EXPR(8);
  }
  __syncthreads();
  int wv = tid >> 6, lane = tid & 63;
  int half = lane >> 5;
  int n = chunk * 128 + wv * 32 + (lane & 31);
  if (n >= N2) return;
  int tt = n >> 2, i = (n >> 1) & 1, j = n & 1;
  int p = ip[tt];
  int ph = p / 31, pw = p - ph * 31;
  int cc = (2 * ph + i) * 62 + (2 * pw + j);
  float t0 = 0.5f * yp0[cc], t1 = 0.5f * yp0[HW2 + cc];
  float t2 = 0.5f * yp0[2 * HW2 + cc], t3 = 0.5f * yp0[3 * HW2 + cc];
  float4 kr = QKV_EXPR(4);
  int mstart = half * 481;
  int mend = half ? N2 : 481;
  float sum = 0.f, a0 = 0.f, a1 = 0.f, a2 = 0.f, a3 = 0.f;
  #pragma unroll 4
  for (int m = mstart; m < mend; m++) {
    float4 q = qvv[2 * m];
    float4 v = qvv[2 * m + 1];
    float s = kr.x * q.x + kr.y * q.y + kr.z * q.z + kr.w * q.w;
    float e = __expf(s);
    sum += e;
    a0 += e * v.x; a1 += e * v.y; a2 += e * v.z; a3 += e * v.w;
  }
  sum += __shfl_xor(sum, 32, 64);
  a0 += __shfl_xor(a0, 32, 64);
  a1 += __shfl_xor(a1, 32, 64);
  a2 += __shfl_xor(a2, 32, 64);
  a3 += __shfl_xor(a3, 32, 64);
  if (half) return;
  float inv = 1.0f / sum;
  size_t oi = (size_t)bg * N2 + n;
  o2[oi] = make_float4(a0 * inv, a1 * inv, a2 * inv, a3 * inv);
  coordg[oi] = cc;
}

// scatter-add attn2 output into yacc (disjoint targets)
__global__ __launch_bounds__(256) void k_scatter(float* __restrict__ yacc,
                                                 const float4* __restrict__ o2,
                                                 const int* __restrict__ coordg) {
  int idx = blockIdx.x * 256 + threadIdx.x;
  if (idx >= 64 * N2) return;
  int bg = idx / N2;
  int b = bg >> 4, g = bg & 15;
  float4 o = o2[idx];
  int cc = coordg[idx];
  float* yp0 = yacc + (size_t)(b * 64 + g * 4) * HW2;
  yp0[cc] += o.x;
  yp0[HW2 + cc] += o.y;
  yp0[2 * HW2 + cc] += o.z;
  yp0[3 * HW2 + cc] += o.w;
}

// depthwise 3x3, pad 1
__global__ __launch_bounds__(256) void k_dwconv(const float* __restrict__ yin,
                                                const float* __restrict__ w,
                                                float* __restrict__ z1) {
  int idx = blockIdx.x * 256 + threadIdx.x;
  if (idx >= 64 * NPIX) return;
  int x = idx % 62; int t = idx / 62;
  int y = t % 62; t /= 62;
  int c = t % 64;
  int plane = idx / HW2;
  const float* yp = yin + (size_t)plane * HW2;
  const float* wp = w + c * 9;
  float acc = 0.f;
  #pragma unroll
  for (int ky = 0; ky < 3; ky++) {
    int yy = y + ky - 1;
    if (yy < 0 || yy > 61) continue;
    #pragma unroll
    for (int kx = 0; kx < 3; kx++) {
      int xx = x + kx - 1;
      if (xx < 0 || xx > 61) continue;
      acc += yp[yy * 62 + xx] * wp[ky * 3 + kx];
    }
  }
  z1[idx] = acc;
}

__device__ __forceinline__ float wave_sum(float x) {
  #pragma unroll
  for (int off = 32; off > 0; off >>= 1) x += __shfl_xor(x, off, 64);
  return x;
}

__global__ __launch_bounds__(256) void k_stats(const float* __restrict__ buf,
                                               float* __restrict__ stats) {
  __shared__ float red[8];
  int c = blockIdx.x >> 2, b = blockIdx.x & 3;
  const float* p = buf + (size_t)(b * 64 + c) * HW2;
  float s = 0.f, s2 = 0.f;
  for (int i = threadIdx.x; i < HW2; i += 256) { float z = p[i]; s += z; s2 += z * z; }
  s = wave_sum(s); s2 = wave_sum(s2);
  int wave = threadIdx.x >> 6, lane = threadIdx.x & 63;
  if (lane == 0) { red[wave] = s; red[4 + wave] = s2; }
  __syncthreads();
  if (threadIdx.x == 0) {
    atomicAdd(&stats[c], red[0] + red[1] + red[2] + red[3]);
    atomicAdd(&stats[64 + c], red[4] + red[5] + red[6] + red[7]);
  }
}

__global__ void k_bnparam(const float* __restrict__ stats, const float* __restrict__ gamma,
                          const float* __restrict__ beta, float* __restrict__ par) {
  int c = threadIdx.x;
  if (c < 64) {
    float m = stats[c] * (1.0f / NPIX);
    float v = stats[64 + c] * (1.0f / NPIX) - m * m;
    float a = gamma[c] * rsqrtf(v + 1e-5f);
    par[c] = a; par[64 + c] = beta[c] - m * a;
  }
}

// pointwise 1x1, co-split x4: grid = pixblocks(61) x cog(4: 16 co)
__global__ __launch_bounds__(256) void k_pwconv(const float* __restrict__ z1,
                                                const float* __restrict__ wpw,
                                                const float* __restrict__ par,
                                                float* __restrict__ z2) {
  __shared__ float w[16 * 64];
  __shared__ float aa[64], cb[64];
  int tid = threadIdx.x;
  int cog = blockIdx.x & 3;
  int pb = blockIdx.x >> 2;
  for (int i = tid; i < 1024; i += 256) w[i] = wpw[cog * 1024 + i];
  if (tid < 64) { aa[tid] = par[tid]; cb[tid] = par[64 + tid]; }
  __syncthreads();
  int pix = pb * 256 + tid;
  if (pix >= NPIX) return;
  int b = pix / HW2, p = pix - b * HW2;
  float h[64];
  #pragma unroll
  for (int ci = 0; ci < 64; ci++) {
    float z = z1[(size_t)(b * 64 + ci) * HW2 + p];
    z = aa[ci] * z + cb[ci];
    h[ci] = fminf(fmaxf(z, 0.f), 6.f);
  }
  #pragma unroll
  for (int cc = 0; cc < 16; cc++) {
    float acc = 0.f;
    #pragma unroll
    for (int ci = 0; ci < 64; ci++) acc += h[ci] * w[cc * 64 + ci];
    z2[(size_t)(b * 64 + cog * 16 + cc) * HW2 + p] = acc;
  }
}

__global__ __launch_bounds__(256) void k_final(const float* __restrict__ z2,
                                               const float* __restrict__ par,
                                               float* __restrict__ out) {
  int idx = blockIdx.x * 256 + threadIdx.x;
  if (idx >= 64 * NPIX) return;
  int c = (idx / HW2) & 63;
  float z = par[c] * z2[idx] + par[64 + c];
  out[idx] = fminf(fmaxf(z, 0.f), 6.f);
}

extern "C" void kernel_launch(void* const* d_in, const int* in_sizes, int n_in,
                              void* d_out, int out_size, void* d_ws, size_t ws_size,
                              hipStream_t stream) {
  const float* x       = (const float*)d_in[0];
  const float* w_down  = (const float*)d_in[1];
  const float* b_down  = (const float*)d_in[2];
  const float* w_qkv_c = (const float*)d_in[3];
  const float* b_qkv_c = (const float*)d_in[4];
  const float* w_up    = (const float*)d_in[5];
  const float* b_up    = (const float*)d_in[6];
  const float* w_qkv_t = (const float*)d_in[7];
  const float* b_qkv_t = (const float*)d_in[8];
  const float* w_dw    = (const float*)d_in[9];
  const float* g_dw    = (const float*)d_in[10];
  const float* be_dw   = (const float*)d_in[11];
  const float* w_pw    = (const float*)d_in[12];
  const float* g_pw    = (const float*)d_in[13];
  const float* be_pw   = (const float*)d_in[14];
  float* out = (float*)d_out;

  float* ws    = (float*)d_ws;
  float* xd    = ws;                       // 492032 = 4*128*961
  float* o1    = xd + 492032;              // 492032
  int*   topk  = (int*)(o1 + 492032);      // 15360 = 4*16*240
  float* yacc  = (float*)(topk + 15360);   // 984064 = 4*64*62*62
  float* z1    = yacc + 984064;            // 984064 (aliases rowstat+coarse pre-dwconv)
  float* z2    = z1 + 984064;              // 984064 (aliases o2+coordg pre-pwconv)
  float* stats = z2 + 984064;              // 256
  float* par   = stats + 256;              // 256

  float*  rowstat = z1;                    // 4*16*961 floats
  float*  coarse  = z1 + 61504;            // 4*16*961 floats
  float4* o2      = (float4*)z2;           // 4*16*960 float4
  int*    coordg  = (int*)(z2 + 245760);   // 61440 ints

  k_zero<<<1, 256, 0, stream>>>(stats, 256);
  k_down<<<512, 256, 0, stream>>>(x, w_down, b_down, xd);
  k_attn1<<<1024, 256, 0, stream>>>(xd, w_qkv_c, b_qkv_c, o1, rowstat);
  k_coarse<<<1024, 256, 0, stream>>>(xd, w_qkv_c, b_qkv_c, rowstat, coarse);
  k_topk<<<64, 256, 0, stream>>>(coarse, topk);
  k_upconv<<<1024, 256, 0, stream>>>(o1, w_up, b_up, yacc);
  k_attn2<<<512, 256, 0, stream>>>(yacc, w_qkv_t, b_qkv_t, topk, o2, coordg);
  k_scatter<<<(64 * N2 + 255) / 256, 256, 0, stream>>>(yacc, o2, coordg);
  k_dwconv<<<(64 * NPIX + 255) / 256, 256, 0, stream>>>(yacc, w_dw, z1);
  k_stats<<<256, 256, 0, stream>>>(z1, stats);
  k_bnparam<<<1, 64, 0, stream>>>(stats, g_dw, be_dw, par);
  k_pwconv<<<244, 256, 0, stream>>>(z1, w_pw, par, z2);
  k_stats<<<256, 256, 0, stream>>>(z2, stats + 128);
  k_bnparam<<<1, 64, 0, stream>>>(stats + 128, g_pw, be_pw, par + 128);
  k_final<<<(64 * NPIX + 255) / 256, 256, 0, stream>>>(z2, par + 128, out);
}

// Round 8
// 372.936 us; speedup vs baseline: 2.5561x; 1.0582x over previous
//
#include <hip/hip_runtime.h>
#include <math.h>

#define N1 961
#define N2 960
#define KF 240
#define HW2 3844   // 62*62
#define NPIX 15376 // 4*62*62
#define XDSZ 492032 // 4*128*961

__global__ void k_zero(float* p, int n) {
  int i = blockIdx.x * 256 + threadIdx.x;
  if (i < n) p[i] = 0.f;
}

// down conv v3: 2x2 px x 4 co per thread, K-split x4, partial outputs.
// grid 512 = b(4) x cog(8) x rowtile(4) x kchunk(4). block: 16 co x (8 x 32 px), 16 ci.
__global__ __launch_bounds__(256) void k_down(const float* __restrict__ x,
                                              const float* __restrict__ w,
                                              float* __restrict__ xdp) {
  __shared__ float iS[8][18][72];
  __shared__ float wS[8][16][16];  // [ci][tap][co16]
  int tid = threadIdx.x;
  int bid = blockIdx.x;
  int kchunk = bid & 3;
  int rowtile = (bid >> 2) & 3;
  int cog = (bid >> 4) & 7;
  int b = bid >> 7;
  int r0 = rowtile * 8;
  int wv = tid >> 6, lane = tid & 63;
  int pc = lane & 15, pr = lane >> 4;
  float acc[4][4];  // [px][co]
  #pragma unroll
  for (int i = 0; i < 4; i++)
    #pragma unroll
    for (int j = 0; j < 4; j++) acc[i][j] = 0.f;
  const float* xb = x + (size_t)b * 64 * 4096;
  for (int ch = 0; ch < 2; ch++) {
    int cibase = kchunk * 16 + ch * 8;
    __syncthreads();
    // stage input rows 2r0..2r0+17 (rows >=64 zero-filled), cols 0..65 (64,65 zero)
    for (int e = tid; e < 8 * 18 * 66; e += 256) {
      int dx = e % 66; int t = e / 66;
      int dy = t % 18; int ci = t / 18;
      int iy = 2 * r0 + dy;
      iS[ci][dy][dx] = (dx < 64 && iy < 64)
                           ? xb[(size_t)(cibase + ci) * 4096 + iy * 64 + dx] : 0.f;
    }
    for (int e = tid; e < 2048; e += 256) {
      int co = e & 15, tap = (e >> 4) & 15, ci = e >> 8;
      wS[ci][tap][co] = w[(size_t)(cog * 16 + co) * 1024 + (cibase + ci) * 16 + tap];
    }
    __syncthreads();
    #pragma unroll
    for (int ci = 0; ci < 8; ci++) {
      float xr[6][6];
      #pragma unroll
      for (int rr = 0; rr < 6; rr++)
        #pragma unroll
        for (int jj = 0; jj < 3; jj++) {
          float2 v2 = *(const float2*)&iS[ci][4 * pr + rr][4 * pc + 2 * jj];
          xr[rr][2 * jj] = v2.x; xr[rr][2 * jj + 1] = v2.y;
        }
      #pragma unroll
      for (int ky = 0; ky < 4; ky++)
        #pragma unroll
        for (int kx = 0; kx < 4; kx++) {
          float4 wq = *(const float4*)&wS[ci][ky * 4 + kx][wv * 4];  // broadcast
          #pragma unroll
          for (int dy2 = 0; dy2 < 2; dy2++)
            #pragma unroll
            for (int dx2 = 0; dx2 < 2; dx2++) {
              float xv = xr[2 * dy2 + ky][2 * dx2 + kx];
              int px = dy2 * 2 + dx2;
              acc[px][0] += wq.x * xv; acc[px][1] += wq.y * xv;
              acc[px][2] += wq.z * xv; acc[px][3] += wq.w * xv;
            }
        }
    }
  }
  float* xo = xdp + (size_t)kchunk * XDSZ + (size_t)b * 128 * N1;
  #pragma unroll
  for (int dy2 = 0; dy2 < 2; dy2++) {
    int r = r0 + 2 * pr + dy2;
    if (r >= 31) continue;
    #pragma unroll
    for (int dx2 = 0; dx2 < 2; dx2++) {
      int c = 2 * pc + dx2;
      if (c >= 31) continue;
      #pragma unroll
      for (int cc = 0; cc < 4; cc++)
        xo[(size_t)(cog * 16 + wv * 4 + cc) * N1 + r * 31 + c] = acc[dy2 * 2 + dx2][cc];
    }
  }
}

// combine 4 K-partials + bias -> xd
__global__ __launch_bounds__(256) void k_combine(const float* __restrict__ xdp,
                                                 const float* __restrict__ bias,
                                                 float* __restrict__ xd) {
  int i = blockIdx.x * 256 + threadIdx.x;
  if (i >= XDSZ) return;
  int co = (i / N1) & 127;
  xd[i] = bias[co] + xdp[i] + xdp[XDSZ + i] + xdp[2 * XDSZ + i] + xdp[3 * XDSZ + i];
}

#define QKV_EXPR(off) make_float4( \
    t0 * Ws[(off)] + t1 * Ws[12 + (off)] + t2 * Ws[24 + (off)] + t3 * Ws[36 + (off)] + Bs[(off)], \
    t0 * Ws[(off)+1] + t1 * Ws[12 + (off)+1] + t2 * Ws[24 + (off)+1] + t3 * Ws[36 + (off)+1] + Bs[(off)+1], \
    t0 * Ws[(off)+2] + t1 * Ws[12 + (off)+2] + t2 * Ws[24 + (off)+2] + t3 * Ws[36 + (off)+2] + Bs[(off)+2], \
    t0 * Ws[(off)+3] + t1 * Ws[12 + (off)+3] + t2 * Ws[24 + (off)+3] + t3 * Ws[36 + (off)+3] + Bs[(off)+3])

// attention 1, single-pass, 2-way m-split per row. grid = 128 bg x 8 chunks of 128 rows.
__global__ __launch_bounds__(256) void k_attn1(const float* __restrict__ xd,
                                               const float* __restrict__ wqkv,
                                               const float* __restrict__ bqkv,
                                               float* __restrict__ o1,
                                               float* __restrict__ rowstat) {
  __shared__ float4 qvv[2 * N1];
  __shared__ float Ws[48], Bs[12];
  int tid = threadIdx.x;
  int chunk = blockIdx.x & 7;
  int bg = blockIdx.x >> 3;
  int b = bg >> 5, g = bg & 31;
  if (tid < 48) Ws[tid] = wqkv[tid];
  if (tid < 12) Bs[tid] = bqkv[tid];
  __syncthreads();
  const float* xp0 = xd + (size_t)(b * 128 + g * 4) * N1;
  for (int nn = tid; nn < N1; nn += 256) {
    float t0 = xp0[nn], t1 = xp0[N1 + nn], t2 = xp0[2 * N1 + nn], t3 = xp0[3 * N1 + nn];
    qvv[2 * nn]     = QKV_EXPR(0);
    qvv[2 * nn + 1] = QKV_EXPR(8);
  }
  __syncthreads();
  int wv = tid >> 6, lane = tid & 63;
  int half = lane >> 5;
  int n = chunk * 128 + wv * 32 + (lane & 31);
  if (n >= N1) return;
  float t0 = xp0[n], t1 = xp0[N1 + n], t2 = xp0[2 * N1 + n], t3 = xp0[3 * N1 + n];
  float4 kr = QKV_EXPR(4);
  int mstart = half * 481;
  int mend = half ? N1 : 481;
  float sum = 0.f, a0 = 0.f, a1 = 0.f, a2 = 0.f, a3 = 0.f;
  #pragma unroll 4
  for (int m = mstart; m < mend; m++) {
    float4 q = qvv[2 * m];
    float4 v = qvv[2 * m + 1];
    float s = kr.x * q.x + kr.y * q.y + kr.z * q.z + kr.w * q.w;
    float e = __expf(s);
    sum += e;
    a0 += e * v.x; a1 += e * v.y; a2 += e * v.z; a3 += e * v.w;
  }
  sum += __shfl_xor(sum, 32, 64);
  a0 += __shfl_xor(a0, 32, 64);
  a1 += __shfl_xor(a1, 32, 64);
  a2 += __shfl_xor(a2, 32, 64);
  a3 += __shfl_xor(a3, 32, 64);
  if (half) return;
  float inv = 1.0f / sum;
  float* o1p = o1 + (size_t)(b * 128 + g * 4) * N1;
  o1p[n] = a0 * inv;
  o1p[N1 + n] = a1 * inv;
  o1p[2 * N1 + n] = a2 * inv;
  o1p[3 * N1 + n] = a3 * inv;
  if (g < 16) rowstat[(size_t)(b * 16 + g) * N1 + n] = inv;
}

// coarse[m] = sum_n exp(s[n,m])*inv_n; 4-way n-split per column.
__global__ __launch_bounds__(256) void k_coarse(const float* __restrict__ xd,
                                                const float* __restrict__ wqkv,
                                                const float* __restrict__ bqkv,
                                                const float* __restrict__ rowstat,
                                                float* __restrict__ coarse) {
  __shared__ float4 kS[N1];
  __shared__ float rs[N1];
  __shared__ float Ws[48], Bs[12];
  int tid = threadIdx.x;
  int chunk = blockIdx.x & 15;
  int bg = blockIdx.x >> 4;
  int b = bg >> 4, g = bg & 15;
  if (tid < 48) Ws[tid] = wqkv[tid];
  if (tid < 12) Bs[tid] = bqkv[tid];
  __syncthreads();
  const float* xp0 = xd + (size_t)(b * 128 + g * 4) * N1;
  const float* rp = rowstat + (size_t)(b * 16 + g) * N1;
  for (int nn = tid; nn < N1; nn += 256) {
    float t0 = xp0[nn], t1 = xp0[N1 + nn], t2 = xp0[2 * N1 + nn], t3 = xp0[3 * N1 + nn];
    kS[nn] = QKV_EXPR(4);
    rs[nn] = rp[nn];
  }
  __syncthreads();
  int wv = tid >> 6, lane = tid & 63;
  int q4 = lane >> 4;
  int m = chunk * 64 + wv * 16 + (lane & 15);
  if (m >= N1) return;
  float t0 = xp0[m], t1 = xp0[N1 + m], t2 = xp0[2 * N1 + m], t3 = xp0[3 * N1 + m];
  float4 q = QKV_EXPR(0);
  int ns = q4 * 241;
  int ne = (ns + 241 < N1) ? ns + 241 : N1;
  float c = 0.f;
  #pragma unroll 4
  for (int n = ns; n < ne; n++) {
    float4 k = kS[n];
    float s = k.x * q.x + k.y * q.y + k.z * q.z + k.w * q.w;
    c += __expf(s) * rs[n];
  }
  c += __shfl_xor(c, 16, 64);
  c += __shfl_xor(c, 32, 64);
  if (q4 == 0) coarse[(size_t)(b * 16 + g) * N1 + m] = c;
}

// top-240 per (b,g<16): bitonic over 1024 packed keys
__global__ __launch_bounds__(256) void k_topk(const float* __restrict__ coarse,
                                              int* __restrict__ topk) {
  __shared__ unsigned long long keys[1024];
  int tid = threadIdx.x;
  int bg = blockIdx.x;
  const float* cp = coarse + (size_t)bg * N1;
  for (int i = tid; i < 1024; i += 256) {
    unsigned long long key = 0ull;
    if (i < N1) {
      unsigned fb = __float_as_uint(cp[i]);
      key = ((unsigned long long)fb << 32) | (unsigned)(N1 - 1 - i);
    }
    keys[i] = key;
  }
  __syncthreads();
  for (int k2 = 2; k2 <= 1024; k2 <<= 1) {
    for (int j = k2 >> 1; j > 0; j >>= 1) {
      for (int i = tid; i < 1024; i += 256) {
        int ixj = i ^ j;
        if (ixj > i) {
          unsigned long long a = keys[i], bb = keys[ixj];
          bool up = ((i & k2) == 0);
          if ((a > bb) == up) { keys[i] = bb; keys[ixj] = a; }
        }
      }
      __syncthreads();
    }
  }
  if (tid < KF) {
    unsigned long long key = keys[1023 - tid];
    topk[(size_t)bg * KF + tid] = (N1 - 1) - (int)(unsigned)(key & 0xffffffffull);
  }
}

// transposed conv, per-parity: o1(4,128,31,31) -> yacc = 2*coarse_out (4,64,62,62)
__global__ __launch_bounds__(256) void k_upconv(const float* __restrict__ o1,
                                                const float* __restrict__ w,
                                                const float* __restrict__ bias,
                                                float* __restrict__ yacc) {
  __shared__ float iS[16][9][12];
  __shared__ float wS[16][4][16];  // [ci][tap][co16]
  int tid = threadIdx.x;
  int bid = blockIdx.x;
  int b = bid >> 8;
  int cog = (bid >> 6) & 3;
  int par = (bid >> 4) & 3;
  int py = par >> 1, px = par & 1;
  int tile = bid & 15;
  int r0 = (tile >> 2) * 8, c0 = (tile & 3) * 8;
  int wv = tid >> 6, lane = tid & 63;
  int pr = lane >> 3, pc = lane & 7;
  int cobase = cog * 16 + wv * 4;
  int wo[4];
  #pragma unroll
  for (int t = 0; t < 4; t++) {
    int a = t >> 1, d = t & 1;
    wo[t] = (3 - (py + 2 * a)) * 4 + (3 - (px + 2 * d));
  }
  float acc[4] = {0.f, 0.f, 0.f, 0.f};
  const float* ob = o1 + (size_t)b * 128 * N1;
  for (int ch = 0; ch < 8; ch++) {
    __syncthreads();
    for (int e = tid; e < 16 * 81; e += 256) {
      int dx = e % 9; int t = e / 9;
      int dy = t % 9; int ci = t / 9;
      int iy = r0 + py - 1 + dy, ix = c0 + px - 1 + dx;
      float v = 0.f;
      if (iy >= 0 && iy < 31 && ix >= 0 && ix < 31)
        v = ob[(size_t)(ch * 16 + ci) * N1 + iy * 31 + ix];
      iS[ci][dy][dx] = v;
    }
    for (int e = tid; e < 1024; e += 256) {
      int co = e & 15, tap = (e >> 4) & 3, ci = e >> 6;
      wS[ci][tap][co] = w[(size_t)(ch * 16 + ci) * 1024 + (cog * 16 + co) * 16 + wo[tap]];
    }
    __syncthreads();
    #pragma unroll
    for (int ci = 0; ci < 16; ci++) {
      float xr[2][2];
      #pragma unroll
      for (int a = 0; a < 2; a++) {
        xr[a][0] = iS[ci][pr + a][pc];
        xr[a][1] = iS[ci][pr + a][pc + 1];
      }
      #pragma unroll
      for (int t = 0; t < 4; t++) {
        float4 wq = *(const float4*)&wS[ci][t][wv * 4];  // broadcast
        float xv = xr[t >> 1][t & 1];
        acc[0] += wq.x * xv; acc[1] += wq.y * xv;
        acc[2] += wq.z * xv; acc[3] += wq.w * xv;
      }
    }
  }
  int r = r0 + pr, c = c0 + pc;
  if (r >= 31 || c >= 31) return;
  int y = 2 * r + py, xx = 2 * c + px;
  #pragma unroll
  for (int cc = 0; cc < 4; cc++) {
    int co = cobase + cc;
    yacc[(size_t)(b * 64 + co) * HW2 + y * 62 + xx] = 2.0f * (acc[cc] + bias[co]);
  }
}

// attention 2, single-pass, 2-way m-split. grid = 64 bg x 8 chunks of 128 rows.
__global__ __launch_bounds__(256) void k_attn2(const float* __restrict__ yacc,
                                               const float* __restrict__ wqkv,
                                               const float* __restrict__ bqkv,
                                               const int* __restrict__ topk,
                                               float4* __restrict__ o2,
                                               int* __restrict__ coordg) {
  __shared__ float4 qvv[2 * N2];
  __shared__ float Ws[48], Bs[12];
  int tid = threadIdx.x;
  int chunk = blockIdx.x & 7;
  int bg = blockIdx.x >> 3;
  int b = bg >> 4, g = bg & 15;
  if (tid < 48) Ws[tid] = wqkv[tid];
  if (tid < 12) Bs[tid] = bqkv[tid];
  __syncthreads();
  const float* yp0 = yacc + (size_t)(b * 64 + g * 4) * HW2;
  const int* ip = topk + (size_t)bg * KF;
  for (int nn = tid; nn < N2; nn += 256) {
    int tt = nn >> 2, i = (nn >> 1) & 1, j = nn & 1;
    int p = ip[tt];
    int ph = p / 31, pw = p - ph * 31;
    int cc = (2 * ph + i) * 62 + (2 * pw + j);
    float t0 = 0.5f * yp0[cc], t1 = 0.5f * yp0[HW2 + cc];
    float t2 = 0.5f * yp0[2 * HW2 + cc], t3 = 0.5f * yp0[3 * HW2 + cc];
    qvv[2 * nn]     = QKV_EXPR(0);
    qvv[2 * nn + 1] = QKV_EXPR(8);
  }
  __syncthreads();
  int wv = tid >> 6, lane = tid & 63;
  int half = lane >> 5;
  int n = chunk * 128 + wv * 32 + (lane & 31);
  if (n >= N2) return;
  int tt = n >> 2, i = (n >> 1) & 1, j = n & 1;
  int p = ip[tt];
  int ph = p / 31, pw = p - ph * 31;
  int cc = (2 * ph + i) * 62 + (2 * pw + j);
  float t0 = 0.5f * yp0[cc], t1 = 0.5f * yp0[HW2 + cc];
  float t2 = 0.5f * yp0[2 * HW2 + cc], t3 = 0.5f * yp0[3 * HW2 + cc];
  float4 kr = QKV_EXPR(4);
  int mstart = half * 481;
  int mend = half ? N2 : 481;
  float sum = 0.f, a0 = 0.f, a1 = 0.f, a2 = 0.f, a3 = 0.f;
  #pragma unroll 4
  for (int m = mstart; m < mend; m++) {
    float4 q = qvv[2 * m];
    float4 v = qvv[2 * m + 1];
    float s = kr.x * q.x + kr.y * q.y + kr.z * q.z + kr.w * q.w;
    float e = __expf(s);
    sum += e;
    a0 += e * v.x; a1 += e * v.y; a2 += e * v.z; a3 += e * v.w;
  }
  sum += __shfl_xor(sum, 32, 64);
  a0 += __shfl_xor(a0, 32, 64);
  a1 += __shfl_xor(a1, 32, 64);
  a2 += __shfl_xor(a2, 32, 64);
  a3 += __shfl_xor(a3, 32, 64);
  if (half) return;
  float inv = 1.0f / sum;
  size_t oi = (size_t)bg * N2 + n;
  o2[oi] = make_float4(a0 * inv, a1 * inv, a2 * inv, a3 * inv);
  coordg[oi] = cc;
}

// scatter-add attn2 output into yacc (disjoint targets)
__global__ __launch_bounds__(256) void k_scatter(float* __restrict__ yacc,
                                                 const float4* __restrict__ o2,
                                                 const int* __restrict__ coordg) {
  int idx = blockIdx.x * 256 + threadIdx.x;
  if (idx >= 64 * N2) return;
  int bg = idx / N2;
  int b = bg >> 4, g = bg & 15;
  float4 o = o2[idx];
  int cc = coordg[idx];
  float* yp0 = yacc + (size_t)(b * 64 + g * 4) * HW2;
  yp0[cc] += o.x;
  yp0[HW2 + cc] += o.y;
  yp0[2 * HW2 + cc] += o.z;
  yp0[3 * HW2 + cc] += o.w;
}

// depthwise 3x3, pad 1
__global__ __launch_bounds__(256) void k_dwconv(const float* __restrict__ yin,
                                                const float* __restrict__ w,
                                                float* __restrict__ z1) {
  int idx = blockIdx.x * 256 + threadIdx.x;
  if (idx >= 64 * NPIX) return;
  int x = idx % 62; int t = idx / 62;
  int y = t % 62; t /= 62;
  int c = t % 64;
  int plane = idx / HW2;
  const float* yp = yin + (size_t)plane * HW2;
  const float* wp = w + c * 9;
  float acc = 0.f;
  #pragma unroll
  for (int ky = 0; ky < 3; ky++) {
    int yy = y + ky - 1;
    if (yy < 0 || yy > 61) continue;
    #pragma unroll
    for (int kx = 0; kx < 3; kx++) {
      int xx = x + kx - 1;
      if (xx < 0 || xx > 61) continue;
      acc += yp[yy * 62 + xx] * wp[ky * 3 + kx];
    }
  }
  z1[idx] = acc;
}

__device__ __forceinline__ float wave_sum(float x) {
  #pragma unroll
  for (int off = 32; off > 0; off >>= 1) x += __shfl_xor(x, off, 64);
  return x;
}

__global__ __launch_bounds__(256) void k_stats(const float* __restrict__ buf,
                                               float* __restrict__ stats) {
  __shared__ float red[8];
  int c = blockIdx.x >> 2, b = blockIdx.x & 3;
  const float* p = buf + (size_t)(b * 64 + c) * HW2;
  float s = 0.f, s2 = 0.f;
  for (int i = threadIdx.x; i < HW2; i += 256) { float z = p[i]; s += z; s2 += z * z; }
  s = wave_sum(s); s2 = wave_sum(s2);
  int wave = threadIdx.x >> 6, lane = threadIdx.x & 63;
  if (lane == 0) { red[wave] = s; red[4 + wave] = s2; }
  __syncthreads();
  if (threadIdx.x == 0) {
    atomicAdd(&stats[c], red[0] + red[1] + red[2] + red[3]);
    atomicAdd(&stats[64 + c], red[4] + red[5] + red[6] + red[7]);
  }
}

__global__ void k_bnparam(const float* __restrict__ stats, const float* __restrict__ gamma,
                          const float* __restrict__ beta, float* __restrict__ par) {
  int c = threadIdx.x;
  if (c < 64) {
    float m = stats[c] * (1.0f / NPIX);
    float v = stats[64 + c] * (1.0f / NPIX) - m * m;
    float a = gamma[c] * rsqrtf(v + 1e-5f);
    par[c] = a; par[64 + c] = beta[c] - m * a;
  }
}

// pointwise 1x1, co-split x4: grid = pixblocks(61) x cog(4: 16 co)
__global__ __launch_bounds__(256) void k_pwconv(const float* __restrict__ z1,
                                                const float* __restrict__ wpw,
                                                const float* __restrict__ par,
                                                float* __restrict__ z2) {
  __shared__ float w[16 * 64];
  __shared__ float aa[64], cb[64];
  int tid = threadIdx.x;
  int cog = blockIdx.x & 3;
  int pb = blockIdx.x >> 2;
  for (int i = tid; i < 1024; i += 256) w[i] = wpw[cog * 1024 + i];
  if (tid < 64) { aa[tid] = par[tid]; cb[tid] = par[64 + tid]; }
  __syncthreads();
  int pix = pb * 256 + tid;
  if (pix >= NPIX) return;
  int b = pix / HW2, p = pix - b * HW2;
  float h[64];
  #pragma unroll
  for (int ci = 0; ci < 64; ci++) {
    float z = z1[(size_t)(b * 64 + ci) * HW2 + p];
    z = aa[ci] * z + cb[ci];
    h[ci] = fminf(fmaxf(z, 0.f), 6.f);
  }
  #pragma unroll
  for (int cc = 0; cc < 16; cc++) {
    float acc = 0.f;
    #pragma unroll
    for (int ci = 0; ci < 64; ci++) acc += h[ci] * w[cc * 64 + ci];
    z2[(size_t)(b * 64 + cog * 16 + cc) * HW2 + p] = acc;
  }
}

__global__ __launch_bounds__(256) void k_final(const float* __restrict__ z2,
                                               const float* __restrict__ par,
                                               float* __restrict__ out) {
  int idx = blockIdx.x * 256 + threadIdx.x;
  if (idx >= 64 * NPIX) return;
  int c = (idx / HW2) & 63;
  float z = par[c] * z2[idx] + par[64 + c];
  out[idx] = fminf(fmaxf(z, 0.f), 6.f);
}

extern "C" void kernel_launch(void* const* d_in, const int* in_sizes, int n_in,
                              void* d_out, int out_size, void* d_ws, size_t ws_size,
                              hipStream_t stream) {
  const float* x       = (const float*)d_in[0];
  const float* w_down  = (const float*)d_in[1];
  const float* b_down  = (const float*)d_in[2];
  const float* w_qkv_c = (const float*)d_in[3];
  const float* b_qkv_c = (const float*)d_in[4];
  const float* w_up    = (const float*)d_in[5];
  const float* b_up    = (const float*)d_in[6];
  const float* w_qkv_t = (const float*)d_in[7];
  const float* b_qkv_t = (const float*)d_in[8];
  const float* w_dw    = (const float*)d_in[9];
  const float* g_dw    = (const float*)d_in[10];
  const float* be_dw   = (const float*)d_in[11];
  const float* w_pw    = (const float*)d_in[12];
  const float* g_pw    = (const float*)d_in[13];
  const float* be_pw   = (const float*)d_in[14];
  float* out = (float*)d_out;

  float* ws    = (float*)d_ws;
  float* xd    = ws;                       // 492032 = 4*128*961
  float* o1    = xd + 492032;              // 492032
  int*   topk  = (int*)(o1 + 492032);      // 15360 = 4*16*240
  float* yacc  = (float*)(topk + 15360);   // 984064 = 4*64*62*62
  float* z1    = yacc + 984064;            // 984064
  float* z2    = z1 + 984064;              // 984064
  float* stats = z2 + 984064;              // 256
  float* par   = stats + 256;              // 256

  // disjoint-lifetime aliases:
  float*  xdp     = z1;                    // 4*492032 = 1968128 floats = z1+z2 exactly (pre-attn)
  float*  rowstat = z1;                    // 4*16*961 floats (post-combine)
  float*  coarse  = z1 + 61504;            // 4*16*961 floats
  float4* o2      = (float4*)z2;           // 4*16*960 float4
  int*    coordg  = (int*)(z2 + 245760);   // 61440 ints

  k_zero<<<1, 256, 0, stream>>>(stats, 256);
  k_down<<<512, 256, 0, stream>>>(x, w_down, xdp);
  k_combine<<<(492032 + 255) / 256, 256, 0, stream>>>(xdp, b_down, xd);
  k_attn1<<<1024, 256, 0, stream>>>(xd, w_qkv_c, b_qkv_c, o1, rowstat);
  k_coarse<<<1024, 256, 0, stream>>>(xd, w_qkv_c, b_qkv_c, rowstat, coarse);
  k_topk<<<64, 256, 0, stream>>>(coarse, topk);
  k_upconv<<<1024, 256, 0, stream>>>(o1, w_up, b_up, yacc);
  k_attn2<<<512, 256, 0, stream>>>(yacc, w_qkv_t, b_qkv_t, topk, o2, coordg);
  k_scatter<<<(64 * N2 + 255) / 256, 256, 0, stream>>>(yacc, o2, coordg);
  k_dwconv<<<(64 * NPIX + 255) / 256, 256, 0, stream>>>(yacc, w_dw, z1);
  k_stats<<<256, 256, 0, stream>>>(z1, stats);
  k_bnparam<<<1, 64, 0, stream>>>(stats, g_dw, be_dw, par);
  k_pwconv<<<244, 256, 0, stream>>>(z1, w_pw, par, z2);
  k_stats<<<256, 256, 0, stream>>>(z2, stats + 128);
  k_bnparam<<<1, 64, 0, stream>>>(stats + 128, g_pw, be_pw, par + 128);
  k_final<<<(64 * NPIX + 255) / 256, 256, 0, stream>>>(z2, par + 128, out);
}